// Round 1
// baseline (1020.090 us; speedup 1.0000x reference)
//
#include <hip/hip_runtime.h>
#include <math.h>

#define N_ 2
#define C_ 64
#define D_ 8
#define H_ 96
#define W_ 96
#define G_ 2
#define CG_ 32
#define P_ 27
#define S_ (D_*H_*W_)   // 73728
#define HW_ (H_*W_)     // 9216

__device__ __forceinline__ float gelu_tanh(float x) {
    float x3 = x*x*x;
    float t = tanhf(0.7978845608028654f*(x + 0.044715f*x3));
    return 0.5f*x*(1.0f+t);
}

// pre_cl[(n*S+s)*64+o] = sum_c x[n][c][s] * w_pre[o][c]
__global__ __launch_bounds__(256) void k_pre(const float* __restrict__ x,
                                             const float* __restrict__ w_pre,
                                             float* __restrict__ pre) {
    __shared__ float lx[64*65];
    __shared__ float lw[64*65];
    int b = blockIdx.x;               // 0..2303
    int n = b / 1152;
    int s0 = (b % 1152) * 64;
    int tid = threadIdx.x;
    for (int idx = tid; idx < 4096; idx += 256) {
        int r = idx >> 6, q = idx & 63;
        lx[r*65+q] = x[((size_t)(n*C_ + r))*S_ + s0 + q];   // lx[c][v]
        lw[r*65+q] = w_pre[idx];                             // lw[o][c]
    }
    __syncthreads();
    int o = tid & 63;
    int vg = tid >> 6;
    for (int i = 0; i < 16; ++i) {
        int v = vg*16 + i;
        float acc = 0.f;
        #pragma unroll
        for (int c = 0; c < 64; ++c)
            acc = fmaf(lx[c*65+v], lw[o*65+c], acc);
        pre[((size_t)(n*S_ + s0 + v))*64 + o] = acc;
    }
}

// xproj[(n*S+s)*64+o] = b_in[o] + sum_c pre[..c] * w_in[c][o]
__global__ __launch_bounds__(256) void k_proj(const float* __restrict__ pre,
                                              const float* __restrict__ w_in,
                                              const float* __restrict__ b_in,
                                              float* __restrict__ xproj) {
    __shared__ float lp[64*65];
    __shared__ float lw[64*65];
    int b = blockIdx.x;
    int n = b / 1152;
    int s0 = (b % 1152) * 64;
    int tid = threadIdx.x;
    for (int idx = tid; idx < 4096; idx += 256) {
        int r = idx >> 6, q = idx & 63;
        lp[r*65+q] = pre[((size_t)(n*S_ + s0 + r))*64 + q];  // lp[v][c]
        lw[r*65+q] = w_in[idx];                               // lw[c][o]
    }
    __syncthreads();
    int o = tid & 63;
    int vg = tid >> 6;
    float bo = b_in[o];
    for (int i = 0; i < 16; ++i) {
        int v = vg*16 + i;
        float acc = bo;
        #pragma unroll
        for (int c = 0; c < 64; ++c)
            acc = fmaf(lp[v*65+c], lw[c*65+o], acc);
        xproj[((size_t)(n*S_ + s0 + v))*64 + o] = acc;
    }
}

// depthwise 3x3x3, zero pad, channels-last in/out
__global__ __launch_bounds__(256) void k_dw(const float* __restrict__ pre,
                                            const float* __restrict__ w_dw,
                                            float* __restrict__ dw) {
    __shared__ float lwd[64*27];
    int b = blockIdx.x;               // n*D*H + z*H + y  (1536)
    int y = b % H_;
    int z = (b / H_) % D_;
    int n = b / (D_*H_);
    int tid = threadIdx.x;
    for (int idx = tid; idx < 64*27; idx += 256) lwd[idx] = w_dw[idx];
    __syncthreads();
    int c = tid & 63, xg = tid >> 6;
    for (int xx = 0; xx < 24; ++xx) {
        int xi = xx*4 + xg;
        float acc = 0.f;
        #pragma unroll
        for (int dz = 0; dz < 3; ++dz) {
            int zz = z + dz - 1;
            if (zz < 0 || zz >= D_) continue;
            #pragma unroll
            for (int dy = 0; dy < 3; ++dy) {
                int yy = y + dy - 1;
                if (yy < 0 || yy >= H_) continue;
                #pragma unroll
                for (int dx = 0; dx < 3; ++dx) {
                    int xn = xi + dx - 1;
                    if (xn < 0 || xn >= W_) continue;
                    float v = pre[((size_t)(n*S_) + zz*HW_ + yy*W_ + xn)*64 + c];
                    acc = fmaf(v, lwd[c*27 + (dz*9 + dy*3 + dx)], acc);
                }
            }
        }
        dw[((size_t)(n*S_) + z*HW_ + y*W_ + xi)*64 + c] = acc;
    }
}

// instance-norm partial sums: block per (n, chunk of 1152 voxels)
__global__ __launch_bounds__(256) void k_stats1(const float* __restrict__ dw,
                                                float* __restrict__ psum,
                                                float* __restrict__ pss) {
    __shared__ float ls[4][64], lss[4][64];
    int b = blockIdx.x;               // 0..127
    int n = b >> 6, ch = b & 63;
    size_t base = ((size_t)n*S_ + (size_t)ch*1152)*64;
    int c = threadIdx.x & 63, vg = threadIdx.x >> 6;
    float s = 0.f, ss = 0.f;
    for (int v = vg; v < 1152; v += 4) {
        float val = dw[base + (size_t)v*64 + c];
        s += val;
        ss = fmaf(val, val, ss);
    }
    ls[vg][c] = s; lss[vg][c] = ss;
    __syncthreads();
    if (threadIdx.x < 64) {
        psum[b*64 + c] = ls[0][c]+ls[1][c]+ls[2][c]+ls[3][c];
        pss [b*64 + c] = lss[0][c]+lss[1][c]+lss[2][c]+lss[3][c];
    }
}

__global__ void k_stats2(const float* __restrict__ psum, const float* __restrict__ pss,
                         float* __restrict__ stats) {
    int t = threadIdx.x;              // 0..127
    if (t >= 128) return;
    int n = t >> 6, c = t & 63;
    float s = 0.f, ss = 0.f;
    for (int ch = 0; ch < 64; ++ch) {
        s  += psum[(n*64+ch)*64 + c];
        ss += pss [(n*64+ch)*64 + c];
    }
    float inv = 1.f / (float)S_;
    float mean = s * inv;
    float var = ss * inv - mean*mean;
    stats[n*128 + c] = mean;
    stats[n*128 + 64 + c] = rsqrtf(var + 1e-5f);
}

// W2[c2][o] = sum_c w_out[c2][c]*w_post[o][c] ; B2[o] = sum_c w_post[o][c]*b_out[c]
__global__ void k_w2(const float* __restrict__ w_out, const float* __restrict__ b_out,
                     const float* __restrict__ w_post, float* __restrict__ W2,
                     float* __restrict__ B2) {
    int tid = threadIdx.x;
    for (int idx = tid; idx < 4096; idx += 256) {
        int c2 = idx >> 6, o = idx & 63;
        float acc = 0.f;
        for (int c = 0; c < 64; ++c)
            acc = fmaf(w_out[c2*64+c], w_post[o*64+c], acc);
        W2[c2*64 + o] = acc;
    }
    if (tid < 64) {
        float acc = 0.f;
        for (int c = 0; c < 64; ++c)
            acc = fmaf(w_post[tid*64+c], b_out[c], acc);
        B2[tid] = acc;
    }
}

// fused: norm+gelu feat, offset/mask projection, softmax, trilinear deformable gather
// half-wave (32 lanes) per (voxel, g); phase1 lane=p, phase2 lane=channel
__global__ __launch_bounds__(256) void k_dcn(const float* __restrict__ xproj,
                                             const float* __restrict__ dw,
                                             const float* __restrict__ stats,
                                             const float* __restrict__ w_off,
                                             const float* __restrict__ b_off,
                                             const float* __restrict__ w_mask,
                                             const float* __restrict__ b_mask,
                                             float* __restrict__ core) {
    __shared__ float featL[8][64];
    int tid = threadIdx.x;
    int lane = tid & 31;
    int pl = tid >> 5;                         // 0..7
    long long pair = (long long)blockIdx.x*8 + pl;   // < 294912
    int g = (int)(pair & 1);
    int vox = (int)(pair >> 1);                // 0..147455 (includes n)
    int n = vox / S_;
    int zyx = vox % S_;
    int z = zyx / HW_;
    int y = (zyx / W_) % H_;
    int xq = zyx % W_;

    for (int c = lane; c < 64; c += 32) {
        float v = dw[(size_t)vox*64 + c];
        float mu = stats[n*128 + c];
        float is = stats[n*128 + 64 + c];
        featL[pl][c] = gelu_tanh((v - mu) * is);
    }
    __syncthreads();

    // phase 1: lane p computes its tap's 3 offsets + mask logit
    int pp = (lane < P_) ? lane : (P_-1);
    int j3 = (g*P_ + pp)*3;
    float accx = b_off[j3], accy = b_off[j3+1], accz = b_off[j3+2];
    float accm = b_mask[g*P_ + pp];
    for (int c = 0; c < 64; ++c) {
        float f = featL[pl][c];
        const float* wo = w_off + c*162 + j3;
        accx = fmaf(f, wo[0], accx);
        accy = fmaf(f, wo[1], accy);
        accz = fmaf(f, wo[2], accz);
        accm = fmaf(f, w_mask[c*54 + g*P_ + pp], accm);
    }
    accx *= 0.5f;                     // AXIS_SCALE on dx
    if (lane >= P_) accm = -INFINITY;
    float mx = accm;
    #pragma unroll
    for (int o2 = 16; o2 >= 1; o2 >>= 1)
        mx = fmaxf(mx, __shfl_xor(mx, o2, 32));
    float e = (lane < P_) ? expf(accm - mx) : 0.f;
    float ssum = e;
    #pragma unroll
    for (int o2 = 16; o2 >= 1; o2 >>= 1)
        ssum += __shfl_xor(ssum, o2, 32);
    float mval = e / ssum;

    // phase 2: lane = channel within group
    int cb = g*32 + lane;
    const float* xpn = xproj + (size_t)(n*S_)*64 + cb;
    float acc = 0.f;
    for (int p = 0; p < P_; ++p) {
        float dxo = __shfl(accx, p, 32);
        float dyo = __shfl(accy, p, 32);
        float dzo = __shfl(accz, p, 32);
        float m   = __shfl(mval, p, 32);
        int kz = p / 9, ky = (p / 3) % 3, kx = p % 3;
        float zf = (float)(z + kz - 1) + dzo;   // unpadded frame
        float yf = (float)(y + ky - 1) + dyo;
        float xf = (float)(xq + kx - 1) + dxo;
        float z0f = floorf(zf), y0f = floorf(yf), x0f = floorf(xf);
        float fz = zf - z0f, fy = yf - y0f, fx = xf - x0f;
        int z0 = (int)z0f, y0 = (int)y0f, x0 = (int)x0f;
        float csum = 0.f;
        #pragma unroll
        for (int c8 = 0; c8 < 8; ++c8) {
            int dz2 = c8 >> 2, dy2 = (c8 >> 1) & 1, dx2 = c8 & 1;
            int zi = z0 + dz2, yi = y0 + dy2, xi2 = x0 + dx2;
            float wz = dz2 ? fz : 1.f - fz;
            float wy = dy2 ? fy : 1.f - fy;
            float wx = dx2 ? fx : 1.f - fx;
            bool inb = (zi >= 0) && (zi < D_) && (yi >= 0) && (yi < H_)
                    && (xi2 >= 0) && (xi2 < W_);
            float val = 0.f;
            if (inb)
                val = xpn[((long long)(zi*HW_ + yi*W_ + xi2))*64];
            csum = fmaf(wz*wy*wx, val, csum);
        }
        acc = fmaf(m, csum, acc);
    }
    core[(size_t)vox*64 + cb] = acc;
}

// out[n][o][s] = x + sigmoid(gate) * (core . W2[:,o] + B2[o])
__global__ __launch_bounds__(256) void k_final(const float* __restrict__ core,
                                               const float* __restrict__ W2,
                                               const float* __restrict__ B2,
                                               const float* __restrict__ x,
                                               const float* __restrict__ gate,
                                               float* __restrict__ out) {
    __shared__ float lc[64*65];
    __shared__ float lw[64*65];
    int b = blockIdx.x;
    int n = b / 1152;
    int s0 = (b % 1152) * 64;
    int tid = threadIdx.x;
    for (int idx = tid; idx < 4096; idx += 256) {
        int r = idx >> 6, q = idx & 63;
        lc[r*65+q] = core[((size_t)(n*S_ + s0 + r))*64 + q];  // lc[v][c]
        lw[r*65+q] = W2[idx];                                  // lw[c][o]
    }
    __syncthreads();
    float sg = 1.f / (1.f + expf(-gate[0]));
    int v = tid & 63, og = tid >> 6;
    for (int i = 0; i < 16; ++i) {
        int o = og*16 + i;
        float acc = B2[o];
        #pragma unroll
        for (int c = 0; c < 64; ++c)
            acc = fmaf(lc[v*65+c], lw[c*65+o], acc);
        size_t gi = ((size_t)(n*64 + o))*S_ + s0 + v;
        out[gi] = fmaf(sg, acc, x[gi]);
    }
}

extern "C" void kernel_launch(void* const* d_in, const int* in_sizes, int n_in,
                              void* d_out, int out_size, void* d_ws, size_t ws_size,
                              hipStream_t stream) {
    const float* x      = (const float*)d_in[0];
    const float* w_pre  = (const float*)d_in[1];
    const float* w_in   = (const float*)d_in[2];
    const float* b_in   = (const float*)d_in[3];
    const float* w_dw   = (const float*)d_in[4];
    const float* w_off  = (const float*)d_in[5];
    const float* b_off  = (const float*)d_in[6];
    const float* w_mask = (const float*)d_in[7];
    const float* b_mask = (const float*)d_in[8];
    const float* w_out  = (const float*)d_in[9];
    const float* b_out  = (const float*)d_in[10];
    const float* w_post = (const float*)d_in[11];
    const float* gate   = (const float*)d_in[12];
    float* out = (float*)d_out;

    float* ws    = (float*)d_ws;
    float* buf0  = ws;                        // pre, later core
    float* buf1  = buf0 + (size_t)9437184;    // xproj
    float* psum  = buf1 + (size_t)9437184;
    float* pss   = psum + 8192;
    float* stats = pss + 8192;
    float* W2    = stats + 256;
    float* B2    = W2 + 4096;
    float* dwb   = out;                       // d_out doubles as dw scratch

    hipLaunchKernelGGL(k_w2,     dim3(1),     dim3(256), 0, stream, w_out, b_out, w_post, W2, B2);
    hipLaunchKernelGGL(k_pre,    dim3(2304),  dim3(256), 0, stream, x, w_pre, buf0);
    hipLaunchKernelGGL(k_proj,   dim3(2304),  dim3(256), 0, stream, buf0, w_in, b_in, buf1);
    hipLaunchKernelGGL(k_dw,     dim3(1536),  dim3(256), 0, stream, buf0, w_dw, dwb);
    hipLaunchKernelGGL(k_stats1, dim3(128),   dim3(256), 0, stream, dwb, psum, pss);
    hipLaunchKernelGGL(k_stats2, dim3(1),     dim3(128), 0, stream, psum, pss, stats);
    hipLaunchKernelGGL(k_dcn,    dim3(36864), dim3(256), 0, stream, buf1, dwb, stats,
                       w_off, b_off, w_mask, b_mask, buf0);
    hipLaunchKernelGGL(k_final,  dim3(2304),  dim3(256), 0, stream, buf0, W2, B2, x, gate, out);
}

// Round 2
// 657.660 us; speedup vs baseline: 1.5511x; 1.5511x over previous
//
#include <hip/hip_runtime.h>
#include <math.h>

#define N_ 2
#define C_ 64
#define D_ 8
#define H_ 96
#define W_ 96
#define G_ 2
#define P_ 27
#define S_ (D_*H_*W_)   // 73728
#define HW_ (H_*W_)     // 9216

__device__ __forceinline__ float gelu_tanh(float x) {
    float x3 = x*x*x;
    float t = tanhf(0.7978845608028654f*(x + 0.044715f*x3));
    return 0.5f*x*(1.0f+t);
}

// pre[(n*S+s)*64+o] = sum_c x[n][c][s] * w_pre[o][c]   (4x4 register blocked)
__global__ __launch_bounds__(256) void k_pre(const float* __restrict__ x,
                                             const float* __restrict__ w_pre,
                                             float* __restrict__ pre) {
    __shared__ float lx[64][65];   // [c][v]
    __shared__ float lw[64][65];   // [o][c]
    int b = blockIdx.x;
    int n = b / 1152;
    int s0 = (b % 1152) * 64;
    int tid = threadIdx.x;
    for (int idx = tid; idx < 4096; idx += 256) {
        int r = idx >> 6, q = idx & 63;
        lx[r][q] = x[((size_t)(n*C_ + r))*S_ + s0 + q];
        lw[r][q] = w_pre[idx];
    }
    __syncthreads();
    int o0 = (tid & 15) * 4;
    int v0 = (tid >> 4) * 4;
    float acc[4][4] = {};
    #pragma unroll 8
    for (int c = 0; c < 64; ++c) {
        float xv[4], wv[4];
        #pragma unroll
        for (int j = 0; j < 4; ++j) { xv[j] = lx[c][v0+j]; wv[j] = lw[o0+j][c]; }
        #pragma unroll
        for (int vj = 0; vj < 4; ++vj)
            #pragma unroll
            for (int oj = 0; oj < 4; ++oj)
                acc[vj][oj] = fmaf(xv[vj], wv[oj], acc[vj][oj]);
    }
    #pragma unroll
    for (int vj = 0; vj < 4; ++vj) {
        float4 r = make_float4(acc[vj][0], acc[vj][1], acc[vj][2], acc[vj][3]);
        *(float4*)&pre[((size_t)(n*S_ + s0 + v0 + vj))*64 + o0] = r;
    }
}

// xproj = pre @ w_in + b_in
__global__ __launch_bounds__(256) void k_proj(const float* __restrict__ pre,
                                              const float* __restrict__ w_in,
                                              const float* __restrict__ b_in,
                                              float* __restrict__ xproj) {
    __shared__ float lp[64][65];   // [v][c]
    __shared__ float lw[64][65];   // [c][o]
    int b = blockIdx.x;
    int n = b / 1152;
    int s0 = (b % 1152) * 64;
    int tid = threadIdx.x;
    for (int idx = tid; idx < 4096; idx += 256) {
        int r = idx >> 6, q = idx & 63;
        lp[r][q] = pre[((size_t)(n*S_ + s0 + r))*64 + q];
        lw[r][q] = w_in[idx];
    }
    __syncthreads();
    int o0 = (tid & 15) * 4;
    int v0 = (tid >> 4) * 4;
    float acc[4][4];
    #pragma unroll
    for (int oj = 0; oj < 4; ++oj) {
        float bo = b_in[o0+oj];
        #pragma unroll
        for (int vj = 0; vj < 4; ++vj) acc[vj][oj] = bo;
    }
    #pragma unroll 8
    for (int c = 0; c < 64; ++c) {
        float fv[4], wv[4];
        #pragma unroll
        for (int j = 0; j < 4; ++j) { fv[j] = lp[v0+j][c]; wv[j] = lw[c][o0+j]; }
        #pragma unroll
        for (int vj = 0; vj < 4; ++vj)
            #pragma unroll
            for (int oj = 0; oj < 4; ++oj)
                acc[vj][oj] = fmaf(fv[vj], wv[oj], acc[vj][oj]);
    }
    #pragma unroll
    for (int vj = 0; vj < 4; ++vj) {
        float4 r = make_float4(acc[vj][0], acc[vj][1], acc[vj][2], acc[vj][3]);
        *(float4*)&xproj[((size_t)(n*S_ + s0 + v0 + vj))*64 + o0] = r;
    }
}

// depthwise 3x3x3, zero pad, channels-last in/out
__global__ __launch_bounds__(256) void k_dw(const float* __restrict__ pre,
                                            const float* __restrict__ w_dw,
                                            float* __restrict__ dw) {
    __shared__ float lwd[64*27];
    int b = blockIdx.x;               // n*D*H + z*H + y
    int y = b % H_;
    int z = (b / H_) % D_;
    int n = b / (D_*H_);
    int tid = threadIdx.x;
    for (int idx = tid; idx < 64*27; idx += 256) lwd[idx] = w_dw[idx];
    __syncthreads();
    int c = tid & 63, xg = tid >> 6;
    for (int xx = 0; xx < 24; ++xx) {
        int xi = xx*4 + xg;
        float acc = 0.f;
        #pragma unroll
        for (int dz = 0; dz < 3; ++dz) {
            int zz = z + dz - 1;
            if (zz < 0 || zz >= D_) continue;
            #pragma unroll
            for (int dy = 0; dy < 3; ++dy) {
                int yy = y + dy - 1;
                if (yy < 0 || yy >= H_) continue;
                #pragma unroll
                for (int dx = 0; dx < 3; ++dx) {
                    int xn = xi + dx - 1;
                    if (xn < 0 || xn >= W_) continue;
                    float v = pre[((size_t)(n*S_) + zz*HW_ + yy*W_ + xn)*64 + c];
                    acc = fmaf(v, lwd[c*27 + (dz*9 + dy*3 + dx)], acc);
                }
            }
        }
        dw[((size_t)(n*S_) + z*HW_ + y*W_ + xi)*64 + c] = acc;
    }
}

// instance-norm partials: 1024 blocks, each 144 voxels; psum layout [c][1024]
__global__ __launch_bounds__(256) void k_stats1(const float* __restrict__ dw,
                                                float* __restrict__ psum,
                                                float* __restrict__ pss) {
    __shared__ float ls[4][64], lss[4][64];
    int b = blockIdx.x;               // 0..1023  (n = b>>9)
    int n = b >> 9, ch = b & 511;
    size_t base = ((size_t)(n*S_) + (size_t)ch*144)*64;
    int c = threadIdx.x & 63, vg = threadIdx.x >> 6;
    float s = 0.f, ss = 0.f;
    for (int v = vg; v < 144; v += 4) {
        float val = dw[base + (size_t)v*64 + c];
        s += val;
        ss = fmaf(val, val, ss);
    }
    ls[vg][c] = s; lss[vg][c] = ss;
    __syncthreads();
    if (threadIdx.x < 64) {
        int cc = threadIdx.x;
        psum[cc*1024 + b] = ls[0][cc]+ls[1][cc]+ls[2][cc]+ls[3][cc];
        pss [cc*1024 + b] = lss[0][cc]+lss[1][cc]+lss[2][cc]+lss[3][cc];
    }
}

// final stats: one 64-thread block per (n,c)
__global__ void k_stats2(const float* __restrict__ psum, const float* __restrict__ pss,
                         float* __restrict__ stats) {
    int u = blockIdx.x;               // 0..127
    int n = u >> 6, c = u & 63;
    int l = threadIdx.x;              // 0..63
    float s = 0.f, ss = 0.f;
    #pragma unroll
    for (int k = 0; k < 8; ++k) {
        s  += psum[c*1024 + n*512 + k*64 + l];
        ss += pss [c*1024 + n*512 + k*64 + l];
    }
    #pragma unroll
    for (int o2 = 32; o2 >= 1; o2 >>= 1) {
        s  += __shfl_xor(s, o2);
        ss += __shfl_xor(ss, o2);
    }
    if (l == 0) {
        float inv = 1.f / (float)S_;
        float mean = s * inv;
        float var = ss * inv - mean*mean;
        stats[n*128 + c] = mean;
        stats[n*128 + 64 + c] = rsqrtf(var + 1e-5f);
    }
}

// W2[c2][o] = sum_c w_out[c2][c]*w_post[o][c] ; B2[o] = sum_c w_post[o][c]*b_out[c]
__global__ void k_w2(const float* __restrict__ w_out, const float* __restrict__ b_out,
                     const float* __restrict__ w_post, float* __restrict__ W2,
                     float* __restrict__ B2) {
    int tid = threadIdx.x;
    for (int idx = tid; idx < 4096; idx += 256) {
        int c2 = idx >> 6, o = idx & 63;
        float acc = 0.f;
        for (int c = 0; c < 64; ++c)
            acc = fmaf(w_out[c2*64+c], w_post[o*64+c], acc);
        W2[c2*64 + o] = acc;
    }
    if (tid < 64) {
        float acc = 0.f;
        for (int c = 0; c < 64; ++c)
            acc = fmaf(w_post[tid*64+c], b_out[c], acc);
        B2[tid] = acc;
    }
}

// fused DCN: block = 16 voxels (32 pairs). Phase 1a: feat=gelu(norm(dw)) in LDS.
// Phase 1b: offset/mask projection, thread=(g,p)x4vox. Softmax per (v,g).
// Phase 2: 8 lanes per pair, float4 channel gather.
__global__ __launch_bounds__(256) void k_dcn(const float* __restrict__ xproj,
                                             const float* __restrict__ dw,
                                             const float* __restrict__ stats,
                                             const float* __restrict__ w_off,
                                             const float* __restrict__ b_off,
                                             const float* __restrict__ w_mask,
                                             const float* __restrict__ b_mask,
                                             float* __restrict__ core) {
    __shared__ float featL[16][65];
    __shared__ float4 tapd[32][27];   // dx,dy,dz,m per (pairLocal, p)
    __shared__ float ml[16][54];      // mask logits
    int tid = threadIdx.x;
    int v0 = blockIdx.x * 16;         // S_ % 16 == 0, so n uniform per block
    int n = v0 / S_;

    // phase 1a: feat tile
    for (int k = tid; k < 1024; k += 256) {
        int vi = k >> 6, c = k & 63;
        float val = dw[((size_t)(v0 + vi))*64 + c];
        featL[vi][c] = gelu_tanh((val - stats[n*128+c]) * stats[n*128+64+c]);
    }
    __syncthreads();

    // phase 1b: projection (216 threads: u=(g,p), vi4 = voxel quad)
    if (tid < 216) {
        int u = tid % 54;
        int vi4 = tid / 54;
        int j3 = u*3;
        float bx = b_off[j3], by = b_off[j3+1], bz = b_off[j3+2], bm = b_mask[u];
        float ax[4], ay[4], az[4], am[4];
        #pragma unroll
        for (int j = 0; j < 4; ++j) { ax[j]=bx; ay[j]=by; az[j]=bz; am[j]=bm; }
        for (int c = 0; c < 64; ++c) {
            float w0 = w_off[c*162 + j3];
            float w1 = w_off[c*162 + j3 + 1];
            float w2 = w_off[c*162 + j3 + 2];
            float wm = w_mask[c*54 + u];
            #pragma unroll
            for (int j = 0; j < 4; ++j) {
                float f = featL[vi4*4 + j][c];
                ax[j] = fmaf(f, w0, ax[j]);
                ay[j] = fmaf(f, w1, ay[j]);
                az[j] = fmaf(f, w2, az[j]);
                am[j] = fmaf(f, wm, am[j]);
            }
        }
        int g = u / 27, p = u % 27;
        #pragma unroll
        for (int j = 0; j < 4; ++j) {
            int vloc = vi4*4 + j;
            int pl = vloc*2 + g;
            tapd[pl][p].x = ax[j]*0.5f;   // AXIS_SCALE on dx
            tapd[pl][p].y = ay[j];
            tapd[pl][p].z = az[j];
            ml[vloc][u] = am[j];
        }
    }
    __syncthreads();

    // softmax per (v,g): 32 threads
    if (tid < 32) {
        int v = tid >> 1, g = tid & 1;
        int pl = v*2 + g;
        float mx = -1e30f;
        #pragma unroll
        for (int p = 0; p < 27; ++p) mx = fmaxf(mx, ml[v][g*27+p]);
        float e[27];
        float ssum = 0.f;
        #pragma unroll
        for (int p = 0; p < 27; ++p) { e[p] = __expf(ml[v][g*27+p] - mx); ssum += e[p]; }
        float inv = 1.f / ssum;
        #pragma unroll
        for (int p = 0; p < 27; ++p) tapd[pl][p].w = e[p]*inv;
    }
    __syncthreads();

    // phase 2: 8 lanes per pair, float4 gather
    int lane = tid & 63;
    int wv = tid >> 6;
    int pl = wv*8 + (lane >> 3);
    int vloc = pl >> 1;
    int g = pl & 1;
    int vox = v0 + vloc;
    int zyx = vox - n*S_;
    int z = zyx / HW_;
    int rem = zyx - z*HW_;
    int y = rem / W_;
    int xq = rem - y*W_;
    int cb = n*S_*64 + g*32 + (lane & 7)*4;   // word offset base
    float fzb = (float)(z - 1), fyb = (float)(y - 1), fxb = (float)(xq - 1);
    float a0 = 0.f, a1 = 0.f, a2 = 0.f, a3 = 0.f;
    #pragma unroll
    for (int p = 0; p < 27; ++p) {
        float4 t = tapd[pl][p];
        float zf = fzb + (float)(p/9) + t.z;
        float yf = fyb + (float)((p/3)%3) + t.y;
        float xf = fxb + (float)(p%3) + t.x;
        float z0f = floorf(zf), y0f = floorf(yf), x0f = floorf(xf);
        float fz = zf - z0f, fy = yf - y0f, fx = xf - x0f;
        int z0 = (int)z0f, y0 = (int)y0f, x0 = (int)x0f;
        int z1 = z0 + 1, y1 = y0 + 1, x1 = x0 + 1;
        float m = t.w;
        float wz0 = ((unsigned)z0 < (unsigned)D_) ? (1.f - fz)*m : 0.f;
        float wz1 = ((unsigned)z1 < (unsigned)D_) ? fz*m : 0.f;
        float wy0 = ((unsigned)y0 < (unsigned)H_) ? (1.f - fy) : 0.f;
        float wy1 = ((unsigned)y1 < (unsigned)H_) ? fy : 0.f;
        float wx0 = ((unsigned)x0 < (unsigned)W_) ? (1.f - fx) : 0.f;
        float wx1 = ((unsigned)x1 < (unsigned)W_) ? fx : 0.f;
        int zc0 = min(max(z0, 0), D_-1), zc1 = min(max(z1, 0), D_-1);
        int yc0 = min(max(y0, 0), H_-1), yc1 = min(max(y1, 0), H_-1);
        int xc0 = min(max(x0, 0), W_-1), xc1 = min(max(x1, 0), W_-1);
        int zo0 = zc0*HW_, zo1 = zc1*HW_;
        int yo0 = yc0*W_, yo1 = yc1*W_;
        int xo0 = xc0*64, xo1 = xc1*64;
        int b00 = (zo0 + yo0)*64 + cb;
        int b01 = (zo0 + yo1)*64 + cb;
        int b10 = (zo1 + yo0)*64 + cb;
        int b11 = (zo1 + yo1)*64 + cb;
        float w00 = wz0*wy0, w01 = wz0*wy1, w10 = wz1*wy0, w11 = wz1*wy1;
        const float4 v000 = *(const float4*)(xproj + b00 + xo0);
        const float4 v001 = *(const float4*)(xproj + b00 + xo1);
        const float4 v010 = *(const float4*)(xproj + b01 + xo0);
        const float4 v011 = *(const float4*)(xproj + b01 + xo1);
        const float4 v100 = *(const float4*)(xproj + b10 + xo0);
        const float4 v101 = *(const float4*)(xproj + b10 + xo1);
        const float4 v110 = *(const float4*)(xproj + b11 + xo0);
        const float4 v111 = *(const float4*)(xproj + b11 + xo1);
        float c000 = w00*wx0, c001 = w00*wx1, c010 = w01*wx0, c011 = w01*wx1;
        float c100 = w10*wx0, c101 = w10*wx1, c110 = w11*wx0, c111 = w11*wx1;
        a0 = fmaf(c000, v000.x, a0); a1 = fmaf(c000, v000.y, a1);
        a2 = fmaf(c000, v000.z, a2); a3 = fmaf(c000, v000.w, a3);
        a0 = fmaf(c001, v001.x, a0); a1 = fmaf(c001, v001.y, a1);
        a2 = fmaf(c001, v001.z, a2); a3 = fmaf(c001, v001.w, a3);
        a0 = fmaf(c010, v010.x, a0); a1 = fmaf(c010, v010.y, a1);
        a2 = fmaf(c010, v010.z, a2); a3 = fmaf(c010, v010.w, a3);
        a0 = fmaf(c011, v011.x, a0); a1 = fmaf(c011, v011.y, a1);
        a2 = fmaf(c011, v011.z, a2); a3 = fmaf(c011, v011.w, a3);
        a0 = fmaf(c100, v100.x, a0); a1 = fmaf(c100, v100.y, a1);
        a2 = fmaf(c100, v100.z, a2); a3 = fmaf(c100, v100.w, a3);
        a0 = fmaf(c101, v101.x, a0); a1 = fmaf(c101, v101.y, a1);
        a2 = fmaf(c101, v101.z, a2); a3 = fmaf(c101, v101.w, a3);
        a0 = fmaf(c110, v110.x, a0); a1 = fmaf(c110, v110.y, a1);
        a2 = fmaf(c110, v110.z, a2); a3 = fmaf(c110, v110.w, a3);
        a0 = fmaf(c111, v111.x, a0); a1 = fmaf(c111, v111.y, a1);
        a2 = fmaf(c111, v111.z, a2); a3 = fmaf(c111, v111.w, a3);
    }
    float4 r = make_float4(a0, a1, a2, a3);
    *(float4*)&core[((size_t)vox)*64 + g*32 + (lane & 7)*4] = r;
}

// out[n][o][s] = x + sigmoid(gate) * (core . W2[:,o] + B2[o])
__global__ __launch_bounds__(256) void k_final(const float* __restrict__ core,
                                               const float* __restrict__ W2,
                                               const float* __restrict__ B2,
                                               const float* __restrict__ x,
                                               const float* __restrict__ gate,
                                               float* __restrict__ out) {
    __shared__ float lc[64][65];   // [v][c]
    __shared__ float lw[64][65];   // [c][o]
    int b = blockIdx.x;
    int n = b / 1152;
    int s0 = (b % 1152) * 64;
    int tid = threadIdx.x;
    for (int idx = tid; idx < 4096; idx += 256) {
        int r = idx >> 6, q = idx & 63;
        lc[r][q] = core[((size_t)(n*S_ + s0 + r))*64 + q];
        lw[r][q] = W2[idx];
    }
    __syncthreads();
    float sg = 1.f / (1.f + expf(-gate[0]));
    int o0 = (tid & 15) * 4;
    int v0 = (tid >> 4) * 4;
    float acc[4][4];
    #pragma unroll
    for (int oj = 0; oj < 4; ++oj) {
        float bo = B2[o0+oj];
        #pragma unroll
        for (int vj = 0; vj < 4; ++vj) acc[vj][oj] = bo;
    }
    #pragma unroll 8
    for (int c = 0; c < 64; ++c) {
        float fv[4], wv[4];
        #pragma unroll
        for (int j = 0; j < 4; ++j) { fv[j] = lc[v0+j][c]; wv[j] = lw[c][o0+j]; }
        #pragma unroll
        for (int vj = 0; vj < 4; ++vj)
            #pragma unroll
            for (int oj = 0; oj < 4; ++oj)
                acc[vj][oj] = fmaf(fv[vj], wv[oj], acc[vj][oj]);
    }
    #pragma unroll
    for (int oj = 0; oj < 4; ++oj) {
        size_t gi = ((size_t)(n*64 + o0 + oj))*S_ + s0 + v0;
        float4 xv = *(const float4*)&x[gi];
        float4 r;
        r.x = fmaf(sg, acc[0][oj], xv.x);
        r.y = fmaf(sg, acc[1][oj], xv.y);
        r.z = fmaf(sg, acc[2][oj], xv.z);
        r.w = fmaf(sg, acc[3][oj], xv.w);
        *(float4*)&out[gi] = r;
    }
}

extern "C" void kernel_launch(void* const* d_in, const int* in_sizes, int n_in,
                              void* d_out, int out_size, void* d_ws, size_t ws_size,
                              hipStream_t stream) {
    const float* x      = (const float*)d_in[0];
    const float* w_pre  = (const float*)d_in[1];
    const float* w_in   = (const float*)d_in[2];
    const float* b_in   = (const float*)d_in[3];
    const float* w_dw   = (const float*)d_in[4];
    const float* w_off  = (const float*)d_in[5];
    const float* b_off  = (const float*)d_in[6];
    const float* w_mask = (const float*)d_in[7];
    const float* b_mask = (const float*)d_in[8];
    const float* w_out  = (const float*)d_in[9];
    const float* b_out  = (const float*)d_in[10];
    const float* w_post = (const float*)d_in[11];
    const float* gate   = (const float*)d_in[12];
    float* out = (float*)d_out;

    float* ws    = (float*)d_ws;
    float* buf0  = ws;                        // pre, later core (psum/pss alias its head)
    float* buf1  = buf0 + (size_t)9437184;    // xproj
    float* stats = buf1 + (size_t)9437184;
    float* W2    = stats + 256;
    float* B2    = W2 + 4096;
    float* psum  = buf0;                      // alive only between stats1 and stats2
    float* pss   = buf0 + 65536;              // (pre is dead after k_dw)
    float* dwb   = out;                       // d_out doubles as dw scratch

    hipLaunchKernelGGL(k_w2,     dim3(1),     dim3(256), 0, stream, w_out, b_out, w_post, W2, B2);
    hipLaunchKernelGGL(k_pre,    dim3(2304),  dim3(256), 0, stream, x, w_pre, buf0);
    hipLaunchKernelGGL(k_proj,   dim3(2304),  dim3(256), 0, stream, buf0, w_in, b_in, buf1);
    hipLaunchKernelGGL(k_dw,     dim3(1536),  dim3(256), 0, stream, buf0, w_dw, dwb);
    hipLaunchKernelGGL(k_stats1, dim3(1024),  dim3(256), 0, stream, dwb, psum, pss);
    hipLaunchKernelGGL(k_stats2, dim3(128),   dim3(64),  0, stream, psum, pss, stats);
    hipLaunchKernelGGL(k_dcn,    dim3(9216),  dim3(256), 0, stream, buf1, dwb, stats,
                       w_off, b_off, w_mask, b_mask, buf0);
    hipLaunchKernelGGL(k_final,  dim3(2304),  dim3(256), 0, stream, buf0, W2, B2, x, gate, out);
}

// Round 3
// 608.912 us; speedup vs baseline: 1.6753x; 1.0801x over previous
//
#include <hip/hip_runtime.h>
#include <math.h>

#define N_ 2
#define C_ 64
#define D_ 8
#define H_ 96
#define W_ 96
#define S_ (D_*H_*W_)   // 73728
#define HW_ (H_*W_)     // 9216
// padded xproj: [n][z+2 of 12][y+2 of 100][x+2 of 100][64]
#define ZP_ 12
#define YP_ 100
#define XP_ 100
#define NSTR_ (ZP_*YP_*XP_*64)   // 7680000
#define ZS_ (YP_*XP_*64)         // 640000
#define YS_ (XP_*64)             // 6400

__device__ __forceinline__ float gelu_fast(float x) {
    // 0.5x(1+tanh(a)) = x - x/(exp(2a)+1)
    float a = 0.7978845608028654f * (x + 0.044715f*x*x*x);
    float E = __expf(2.f*a);
    return x - x * __builtin_amdgcn_rcpf(E + 1.f);
}

// prep: W2 = w_out @ w_post^T folded, B2, woffT[c][u] float4 (AXIS_SCALE folded), b4[u]
__global__ __launch_bounds__(64) void k_prep(const float* __restrict__ w_out,
        const float* __restrict__ b_out, const float* __restrict__ w_post,
        const float* __restrict__ w_off, const float* __restrict__ b_off,
        const float* __restrict__ w_mask, const float* __restrict__ b_mask,
        float* __restrict__ W2, float* __restrict__ B2,
        float4* __restrict__ woffT4, float4* __restrict__ b4f) {
    int b = blockIdx.x;      // 0..63
    int t = threadIdx.x;     // 0..63
    float acc = 0.f;
    for (int c = 0; c < 64; ++c)
        acc = fmaf(w_out[b*64+c], w_post[t*64+c], acc);
    W2[b*64 + t] = acc;
    if (b == 0) {
        float a2 = 0.f;
        for (int c = 0; c < 64; ++c)
            a2 = fmaf(w_post[t*64+c], b_out[c], a2);
        B2[t] = a2;
    }
    if (t < 54) {
        int c = b, u = t;
        woffT4[c*64 + u] = make_float4(w_off[c*162 + u*3] * 0.5f,
                                       w_off[c*162 + u*3 + 1],
                                       w_off[c*162 + u*3 + 2],
                                       w_mask[c*54 + u]);
        if (b == 1)
            b4f[u] = make_float4(b_off[u*3] * 0.5f, b_off[u*3+1], b_off[u*3+2],
                                 b_mask[u]);
    }
}

// fused: pre = x @ w_pre^T (write), xprojP = (pre @ w_in + b_in) into padded layout
__global__ __launch_bounds__(256) void k_pre_proj(const float* __restrict__ x,
        const float* __restrict__ w_pre, const float* __restrict__ w_in,
        const float* __restrict__ b_in, float* __restrict__ pre,
        float* __restrict__ xprojP) {
    __shared__ float lx[64][65];    // [c][v] then reused as [v][o]
    __shared__ float lwa[64][65];   // w_pre [o][c]
    __shared__ float lwb[64][65];   // w_in  [c][o]
    int b = blockIdx.x;
    int n = b / 1152;
    int s0 = (b % 1152) * 64;
    int tid = threadIdx.x;
    for (int idx = tid; idx < 1024; idx += 256) {
        int r = idx >> 4, q4 = (idx & 15) * 4;
        float4 vx = *(const float4*)&x[((size_t)(n*C_ + r))*S_ + s0 + q4];
        lx[r][q4] = vx.x; lx[r][q4+1] = vx.y; lx[r][q4+2] = vx.z; lx[r][q4+3] = vx.w;
        float4 va = *(const float4*)&w_pre[r*64 + q4];
        lwa[r][q4] = va.x; lwa[r][q4+1] = va.y; lwa[r][q4+2] = va.z; lwa[r][q4+3] = va.w;
        float4 vb = *(const float4*)&w_in[r*64 + q4];
        lwb[r][q4] = vb.x; lwb[r][q4+1] = vb.y; lwb[r][q4+2] = vb.z; lwb[r][q4+3] = vb.w;
    }
    __syncthreads();
    int o0 = (tid & 15) * 4;
    int v0 = (tid >> 4) * 4;
    float acc[4][4] = {};
    #pragma unroll 8
    for (int c = 0; c < 64; ++c) {
        float xv[4], wv[4];
        #pragma unroll
        for (int j = 0; j < 4; ++j) { xv[j] = lx[c][v0+j]; wv[j] = lwa[o0+j][c]; }
        #pragma unroll
        for (int vj = 0; vj < 4; ++vj)
            #pragma unroll
            for (int oj = 0; oj < 4; ++oj)
                acc[vj][oj] = fmaf(xv[vj], wv[oj], acc[vj][oj]);
    }
    #pragma unroll
    for (int vj = 0; vj < 4; ++vj) {
        float4 r = make_float4(acc[vj][0], acc[vj][1], acc[vj][2], acc[vj][3]);
        *(float4*)&pre[((size_t)(n*S_ + s0 + v0 + vj))*64 + o0] = r;
    }
    __syncthreads();   // done reading lx as [c][v]
    #pragma unroll
    for (int vj = 0; vj < 4; ++vj)
        #pragma unroll
        for (int oj = 0; oj < 4; ++oj)
            lx[v0+vj][o0+oj] = acc[vj][oj];   // now lx = pre tile [v][c2]
    __syncthreads();
    float acc2[4][4];
    #pragma unroll
    for (int oj = 0; oj < 4; ++oj) {
        float bo = b_in[o0+oj];
        #pragma unroll
        for (int vj = 0; vj < 4; ++vj) acc2[vj][oj] = bo;
    }
    #pragma unroll 8
    for (int c = 0; c < 64; ++c) {
        float fv[4], wv[4];
        #pragma unroll
        for (int j = 0; j < 4; ++j) { fv[j] = lx[v0+j][c]; wv[j] = lwb[c][o0+j]; }
        #pragma unroll
        for (int vj = 0; vj < 4; ++vj)
            #pragma unroll
            for (int oj = 0; oj < 4; ++oj)
                acc2[vj][oj] = fmaf(fv[vj], wv[oj], acc2[vj][oj]);
    }
    #pragma unroll
    for (int vj = 0; vj < 4; ++vj) {
        int vox = s0 + v0 + vj;      // within image n
        int z = vox / HW_;
        int rem = vox - z*HW_;
        int y = rem / W_;
        int xq = rem - y*W_;
        size_t pw = (size_t)n*NSTR_ + (size_t)(z+2)*ZS_ + (y+2)*YS_ + (xq+2)*64 + o0;
        float4 r = make_float4(acc2[vj][0], acc2[vj][1], acc2[vj][2], acc2[vj][3]);
        *(float4*)&xprojP[pw] = r;
    }
}

// depthwise 3x3x3 + per-block instance-norm partials
__global__ __launch_bounds__(256) void k_dw_stats(const float* __restrict__ pre,
        const float* __restrict__ w_dw, float* __restrict__ dw,
        float* __restrict__ psum, float* __restrict__ pss) {
    __shared__ float lwd[64*27];
    __shared__ float ls[4][64], lss[4][64];
    int b = blockIdx.x;               // n*D*H + z*H + y  (1536)
    int y = b % H_;
    int z = (b / H_) % D_;
    int n = b / (D_*H_);
    int tid = threadIdx.x;
    for (int idx = tid; idx < 64*27; idx += 256) lwd[idx] = w_dw[idx];
    __syncthreads();
    int c = tid & 63, xg = tid >> 6;
    float s = 0.f, ss = 0.f;
    for (int xx = 0; xx < 24; ++xx) {
        int xi = xx*4 + xg;
        float acc = 0.f;
        #pragma unroll
        for (int dz = 0; dz < 3; ++dz) {
            int zz = z + dz - 1;
            if (zz < 0 || zz >= D_) continue;
            #pragma unroll
            for (int dy = 0; dy < 3; ++dy) {
                int yy = y + dy - 1;
                if (yy < 0 || yy >= H_) continue;
                #pragma unroll
                for (int dx = 0; dx < 3; ++dx) {
                    int xn = xi + dx - 1;
                    if (xn < 0 || xn >= W_) continue;
                    float v = pre[((size_t)(n*S_) + zz*HW_ + yy*W_ + xn)*64 + c];
                    acc = fmaf(v, lwd[c*27 + (dz*9 + dy*3 + dx)], acc);
                }
            }
        }
        dw[((size_t)(n*S_) + z*HW_ + y*W_ + xi)*64 + c] = acc;
        s += acc;
        ss = fmaf(acc, acc, ss);
    }
    ls[xg][c] = s; lss[xg][c] = ss;
    __syncthreads();
    if (tid < 64) {
        psum[tid*1536 + b] = ls[0][tid]+ls[1][tid]+ls[2][tid]+ls[3][tid];
        pss [tid*1536 + b] = lss[0][tid]+lss[1][tid]+lss[2][tid]+lss[3][tid];
    }
}

// reduce partials -> mean / rsqrt(var)
__global__ void k_stats2(const float* __restrict__ psum, const float* __restrict__ pss,
                         float* __restrict__ stats) {
    int u = blockIdx.x;               // 0..127
    int n = u >> 6, c = u & 63;
    int l = threadIdx.x;              // 0..63
    float s = 0.f, ss = 0.f;
    #pragma unroll
    for (int k = 0; k < 12; ++k) {
        int row = n*768 + k*64 + l;
        s  += psum[c*1536 + row];
        ss += pss [c*1536 + row];
    }
    #pragma unroll
    for (int o2 = 32; o2 >= 1; o2 >>= 1) {
        s  += __shfl_xor(s, o2);
        ss += __shfl_xor(ss, o2);
    }
    if (l == 0) {
        float inv = 1.f / (float)S_;
        float mean = s * inv;
        float var = ss * inv - mean*mean;
        stats[n*128 + c] = mean;
        stats[n*128 + 64 + c] = rsqrtf(var + 1e-5f);
    }
}

// fused DCN over 16 voxels / block
__global__ __launch_bounds__(256) void k_dcn(const float* __restrict__ xprojP,
        const float* __restrict__ dw, const float* __restrict__ stats,
        const float4* __restrict__ woffT4, const float4* __restrict__ b4f,
        float* __restrict__ core) {
    __shared__ float featT[64][20];     // [c][vox], b128-aligned stride
    __shared__ float4 offs4[32][33];    // [pair][tap]: dx,dy,dz, logit->prob
    int tid = threadIdx.x;
    int v0 = blockIdx.x * 16;
    int n = (v0 >= S_) ? 1 : 0;
    int zyx0 = v0 - n*S_;
    int z = zyx0 / HW_;
    int rem0 = zyx0 - z*HW_;
    int y = rem0 / W_;
    int xb = rem0 - y*W_;

    // 1a: feat = gelu(instnorm(dw)) transposed into LDS
    {
        int vi = tid >> 4, c4 = (tid & 15) * 4;
        float4 v = *(const float4*)&dw[((size_t)(v0+vi))*64 + c4];
        float vals[4] = {v.x, v.y, v.z, v.w};
        #pragma unroll
        for (int j = 0; j < 4; ++j) {
            int c = c4 + j;
            float t = (vals[j] - stats[n*128+c]) * stats[n*128+64+c];
            featT[c][vi] = gelu_fast(t);
        }
    }
    __syncthreads();

    // 1b: offset/mask projection; thread = (u=(g,p), 4-voxel quad)
    if (tid < 216) {
        int vi4 = tid / 54;
        int u = tid - vi4*54;
        int g = u / 27, p = u - g*27;
        float4 bb = b4f[u];
        float4 a0 = bb, a1 = bb, a2 = bb, a3 = bb;
        for (int c = 0; c < 64; ++c) {
            float4 w = woffT4[c*64 + u];
            float4 f = *(const float4*)&featT[c][vi4*4];
            a0.x = fmaf(f.x, w.x, a0.x); a0.y = fmaf(f.x, w.y, a0.y);
            a0.z = fmaf(f.x, w.z, a0.z); a0.w = fmaf(f.x, w.w, a0.w);
            a1.x = fmaf(f.y, w.x, a1.x); a1.y = fmaf(f.y, w.y, a1.y);
            a1.z = fmaf(f.y, w.z, a1.z); a1.w = fmaf(f.y, w.w, a1.w);
            a2.x = fmaf(f.z, w.x, a2.x); a2.y = fmaf(f.z, w.y, a2.y);
            a2.z = fmaf(f.z, w.z, a2.z); a2.w = fmaf(f.z, w.w, a2.w);
            a3.x = fmaf(f.w, w.x, a3.x); a3.y = fmaf(f.w, w.y, a3.y);
            a3.z = fmaf(f.w, w.z, a3.z); a3.w = fmaf(f.w, w.w, a3.w);
        }
        offs4[(vi4*4+0)*2+g][p] = a0;
        offs4[(vi4*4+1)*2+g][p] = a1;
        offs4[(vi4*4+2)*2+g][p] = a2;
        offs4[(vi4*4+3)*2+g][p] = a3;
    }
    __syncthreads();

    // softmax over taps per pair
    if (tid < 32) {
        float mx = -1e30f;
        #pragma unroll
        for (int p = 0; p < 27; ++p) mx = fmaxf(mx, offs4[tid][p].w);
        float e[27]; float ssum = 0.f;
        #pragma unroll
        for (int p = 0; p < 27; ++p) { e[p] = __expf(offs4[tid][p].w - mx); ssum += e[p]; }
        float inv = __builtin_amdgcn_rcpf(ssum);
        #pragma unroll
        for (int p = 0; p < 27; ++p) offs4[tid][p].w = e[p]*inv;
    }
    __syncthreads();

    // phase 2: 8 lanes x float4 channels per (voxel, g); padded zero-ring -> no bounds tests
    int lane = tid & 63;
    int pl = (tid >> 6)*8 + (lane >> 3);
    int vloc = pl >> 1, g = pl & 1;
    int xq = xb + vloc;               // 16 | 96 so row-uniform block
    const float* basep = xprojP + (size_t)n*NSTR_ + (2*ZS_ + 2*YS_ + 2*64)
                         + g*32 + (lane & 7)*4;
    float fzb = (float)(z-1), fyb = (float)(y-1), fxb = (float)(xq-1);
    float a0 = 0.f, a1 = 0.f, a2 = 0.f, a3 = 0.f;
    #pragma unroll
    for (int p = 0; p < 27; ++p) {
        float4 t = offs4[pl][p];
        float zf = fzb + (float)(p/9) + t.z;
        float yf = fyb + (float)((p/3)%3) + t.y;
        float xf = fxb + (float)(p%3) + t.x;
        zf = fminf(fmaxf(zf, -1.5f), (float)D_ + 0.5f);
        yf = fminf(fmaxf(yf, -1.5f), (float)H_ + 0.5f);
        xf = fminf(fmaxf(xf, -1.5f), (float)W_ + 0.5f);
        float z0f = floorf(zf), y0f = floorf(yf), x0f = floorf(xf);
        float fz = zf - z0f, fy = yf - y0f, fx = xf - x0f;
        int z0 = (int)z0f, y0 = (int)y0f, x0 = (int)x0f;
        float wz1 = fz * t.w, wz0 = t.w - wz1;    // prob folded into z-weights
        float wy1 = fy, wy0 = 1.f - fy;
        float wx1 = fx, wx0 = 1.f - fx;
        float w00 = wz0*wy0, w01 = wz0*wy1, w10 = wz1*wy0, w11 = wz1*wy1;
        float c000 = w00*wx0, c001 = w00*wx1, c010 = w01*wx0, c011 = w01*wx1;
        float c100 = w10*wx0, c101 = w10*wx1, c110 = w11*wx0, c111 = w11*wx1;
        int cw = z0*ZS_ + y0*YS_ + (x0 << 6);
        const float* p00 = basep + cw;
        const float* p01 = p00 + YS_;
        const float* p10 = p00 + ZS_;
        const float* p11 = p10 + YS_;
        float4 v000 = *(const float4*)p00;
        float4 v001 = *(const float4*)(p00 + 64);
        float4 v010 = *(const float4*)p01;
        float4 v011 = *(const float4*)(p01 + 64);
        float4 v100 = *(const float4*)p10;
        float4 v101 = *(const float4*)(p10 + 64);
        float4 v110 = *(const float4*)p11;
        float4 v111 = *(const float4*)(p11 + 64);
        a0 = fmaf(c000, v000.x, a0); a1 = fmaf(c000, v000.y, a1);
        a2 = fmaf(c000, v000.z, a2); a3 = fmaf(c000, v000.w, a3);
        a0 = fmaf(c001, v001.x, a0); a1 = fmaf(c001, v001.y, a1);
        a2 = fmaf(c001, v001.z, a2); a3 = fmaf(c001, v001.w, a3);
        a0 = fmaf(c010, v010.x, a0); a1 = fmaf(c010, v010.y, a1);
        a2 = fmaf(c010, v010.z, a2); a3 = fmaf(c010, v010.w, a3);
        a0 = fmaf(c011, v011.x, a0); a1 = fmaf(c011, v011.y, a1);
        a2 = fmaf(c011, v011.z, a2); a3 = fmaf(c011, v011.w, a3);
        a0 = fmaf(c100, v100.x, a0); a1 = fmaf(c100, v100.y, a1);
        a2 = fmaf(c100, v100.z, a2); a3 = fmaf(c100, v100.w, a3);
        a0 = fmaf(c101, v101.x, a0); a1 = fmaf(c101, v101.y, a1);
        a2 = fmaf(c101, v101.z, a2); a3 = fmaf(c101, v101.w, a3);
        a0 = fmaf(c110, v110.x, a0); a1 = fmaf(c110, v110.y, a1);
        a2 = fmaf(c110, v110.z, a2); a3 = fmaf(c110, v110.w, a3);
        a0 = fmaf(c111, v111.x, a0); a1 = fmaf(c111, v111.y, a1);
        a2 = fmaf(c111, v111.z, a2); a3 = fmaf(c111, v111.w, a3);
    }
    float4 r = make_float4(a0, a1, a2, a3);
    *(float4*)&core[((size_t)(v0 + vloc))*64 + g*32 + (lane & 7)*4] = r;
}

// out = x + sigmoid(gate) * (core @ W2 + B2), back to NCDHW
__global__ __launch_bounds__(256) void k_final(const float* __restrict__ core,
        const float* __restrict__ W2, const float* __restrict__ B2,
        const float* __restrict__ x, const float* __restrict__ gate,
        float* __restrict__ out) {
    __shared__ float lc[64][65];   // [v][c]
    __shared__ float lw[64][65];   // [c][o]
    int b = blockIdx.x;
    int n = b / 1152;
    int s0 = (b % 1152) * 64;
    int tid = threadIdx.x;
    for (int idx = tid; idx < 1024; idx += 256) {
        int r = idx >> 4, q4 = (idx & 15) * 4;
        float4 vc = *(const float4*)&core[((size_t)(n*S_ + s0 + r))*64 + q4];
        lc[r][q4] = vc.x; lc[r][q4+1] = vc.y; lc[r][q4+2] = vc.z; lc[r][q4+3] = vc.w;
        float4 vw = *(const float4*)&W2[r*64 + q4];
        lw[r][q4] = vw.x; lw[r][q4+1] = vw.y; lw[r][q4+2] = vw.z; lw[r][q4+3] = vw.w;
    }
    __syncthreads();
    float sg = 1.f / (1.f + expf(-gate[0]));
    int o0 = (tid & 15) * 4;
    int v0 = (tid >> 4) * 4;
    float acc[4][4];
    #pragma unroll
    for (int oj = 0; oj < 4; ++oj) {
        float bo = B2[o0+oj];
        #pragma unroll
        for (int vj = 0; vj < 4; ++vj) acc[vj][oj] = bo;
    }
    #pragma unroll 8
    for (int c = 0; c < 64; ++c) {
        float fv[4], wv[4];
        #pragma unroll
        for (int j = 0; j < 4; ++j) { fv[j] = lc[v0+j][c]; wv[j] = lw[c][o0+j]; }
        #pragma unroll
        for (int vj = 0; vj < 4; ++vj)
            #pragma unroll
            for (int oj = 0; oj < 4; ++oj)
                acc[vj][oj] = fmaf(fv[vj], wv[oj], acc[vj][oj]);
    }
    #pragma unroll
    for (int oj = 0; oj < 4; ++oj) {
        size_t gi = ((size_t)(n*64 + o0 + oj))*S_ + s0 + v0;
        float4 xv = *(const float4*)&x[gi];
        float4 r;
        r.x = fmaf(sg, acc[0][oj], xv.x);
        r.y = fmaf(sg, acc[1][oj], xv.y);
        r.z = fmaf(sg, acc[2][oj], xv.z);
        r.w = fmaf(sg, acc[3][oj], xv.w);
        *(float4*)&out[gi] = r;
    }
}

extern "C" void kernel_launch(void* const* d_in, const int* in_sizes, int n_in,
                              void* d_out, int out_size, void* d_ws, size_t ws_size,
                              hipStream_t stream) {
    const float* x      = (const float*)d_in[0];
    const float* w_pre  = (const float*)d_in[1];
    const float* w_in   = (const float*)d_in[2];
    const float* b_in   = (const float*)d_in[3];
    const float* w_dw   = (const float*)d_in[4];
    const float* w_off  = (const float*)d_in[5];
    const float* b_off  = (const float*)d_in[6];
    const float* w_mask = (const float*)d_in[7];
    const float* b_mask = (const float*)d_in[8];
    const float* w_out  = (const float*)d_in[9];
    const float* b_out  = (const float*)d_in[10];
    const float* w_post = (const float*)d_in[11];
    const float* gate   = (const float*)d_in[12];
    float* out = (float*)d_out;

    float* ws      = (float*)d_ws;
    float* xprojP  = ws;                               // 15,360,000
    float* preCore = xprojP + (size_t)15360000;        // 9,437,184 (pre, then core)
    float* psum    = preCore + (size_t)9437184;        // 98,304
    float* pss     = psum + 98304;                     // 98,304
    float* stats   = pss + 98304;                      // 256
    float* W2      = stats + 256;                      // 4,096
    float* B2      = W2 + 4096;                        // 64 (+pad)
    float4* woffT4 = (float4*)(B2 + 128);              // 64*64 float4
    float4* b4f    = woffT4 + 4096;                    // 54 float4 (+pad)
    float* dwb     = out;                              // d_out doubles as dw scratch

    hipMemsetAsync(xprojP, 0, (size_t)15360000*4, stream);
    hipLaunchKernelGGL(k_prep,     dim3(64),   dim3(64),  0, stream,
                       w_out, b_out, w_post, w_off, b_off, w_mask, b_mask,
                       W2, B2, woffT4, b4f);
    hipLaunchKernelGGL(k_pre_proj, dim3(2304), dim3(256), 0, stream,
                       x, w_pre, w_in, b_in, preCore, xprojP);
    hipLaunchKernelGGL(k_dw_stats, dim3(1536), dim3(256), 0, stream,
                       preCore, w_dw, dwb, psum, pss);
    hipLaunchKernelGGL(k_stats2,   dim3(128),  dim3(64),  0, stream, psum, pss, stats);
    hipLaunchKernelGGL(k_dcn,      dim3(9216), dim3(256), 0, stream,
                       xprojP, dwb, stats, woffT4, b4f, preCore);
    hipLaunchKernelGGL(k_final,    dim3(2304), dim3(256), 0, stream,
                       preCore, W2, B2, x, gate, out);
}

// Round 4
// 448.358 us; speedup vs baseline: 2.2752x; 1.3581x over previous
//
#include <hip/hip_runtime.h>
#include <math.h>

#define N_ 2
#define C_ 64
#define D_ 8
#define H_ 96
#define W_ 96
#define S_ (D_*H_*W_)   // 73728
#define HW_ (H_*W_)     // 9216
// padded xproj: [n][z+2 of 12][y+2 of 100][x+2 of 100][64]
#define ZP_ 12
#define YP_ 100
#define XP_ 100
#define NSTR_ (ZP_*YP_*XP_*64)   // 7680000
#define ZS_ (YP_*XP_*64)         // 640000
#define YS_ (XP_*64)             // 6400

__device__ __forceinline__ float gelu_fast(float x) {
    // 0.5x(1+tanh(a)) = x - x/(exp(2a)+1)
    float a = 0.7978845608028654f * (x + 0.044715f*x*x*x);
    float E = __expf(2.f*a);
    return x - x * __builtin_amdgcn_rcpf(E + 1.f);
}

// prep: W2 = w_out @ w_post^T folded, B2, woffT[c][u] float4 (AXIS_SCALE folded), b4[u]
__global__ __launch_bounds__(64) void k_prep(const float* __restrict__ w_out,
        const float* __restrict__ b_out, const float* __restrict__ w_post,
        const float* __restrict__ w_off, const float* __restrict__ b_off,
        const float* __restrict__ w_mask, const float* __restrict__ b_mask,
        float* __restrict__ W2, float* __restrict__ B2,
        float4* __restrict__ woffT4, float4* __restrict__ b4f) {
    int b = blockIdx.x;      // 0..63
    int t = threadIdx.x;     // 0..63
    float acc = 0.f;
    for (int c = 0; c < 64; ++c)
        acc = fmaf(w_out[b*64+c], w_post[t*64+c], acc);
    W2[b*64 + t] = acc;
    if (b == 0) {
        float a2 = 0.f;
        for (int c = 0; c < 64; ++c)
            a2 = fmaf(w_post[t*64+c], b_out[c], a2);
        B2[t] = a2;
    }
    if (t < 54) {
        int c = b, u = t;
        woffT4[c*64 + u] = make_float4(w_off[c*162 + u*3] * 0.5f,
                                       w_off[c*162 + u*3 + 1],
                                       w_off[c*162 + u*3 + 2],
                                       w_mask[c*54 + u]);
        if (b == 1)
            b4f[u] = make_float4(b_off[u*3] * 0.5f, b_off[u*3+1], b_off[u*3+2],
                                 b_mask[u]);
    }
}

// fused: pre = x @ w_pre^T (write), xprojP = (pre @ w_in + b_in) into padded layout
__global__ __launch_bounds__(256) void k_pre_proj(const float* __restrict__ x,
        const float* __restrict__ w_pre, const float* __restrict__ w_in,
        const float* __restrict__ b_in, float* __restrict__ pre,
        float* __restrict__ xprojP) {
    __shared__ float lx[64][65];    // [c][v] then reused as [v][o]
    __shared__ float lwa[64][65];   // w_pre [o][c]
    __shared__ float lwb[64][65];   // w_in  [c][o]
    int b = blockIdx.x;
    int n = b / 1152;
    int s0 = (b % 1152) * 64;
    int tid = threadIdx.x;
    for (int idx = tid; idx < 1024; idx += 256) {
        int r = idx >> 4, q4 = (idx & 15) * 4;
        float4 vx = *(const float4*)&x[((size_t)(n*C_ + r))*S_ + s0 + q4];
        lx[r][q4] = vx.x; lx[r][q4+1] = vx.y; lx[r][q4+2] = vx.z; lx[r][q4+3] = vx.w;
        float4 va = *(const float4*)&w_pre[r*64 + q4];
        lwa[r][q4] = va.x; lwa[r][q4+1] = va.y; lwa[r][q4+2] = va.z; lwa[r][q4+3] = va.w;
        float4 vb = *(const float4*)&w_in[r*64 + q4];
        lwb[r][q4] = vb.x; lwb[r][q4+1] = vb.y; lwb[r][q4+2] = vb.z; lwb[r][q4+3] = vb.w;
    }
    __syncthreads();
    int o0 = (tid & 15) * 4;
    int v0 = (tid >> 4) * 4;
    float acc[4][4] = {};
    #pragma unroll 8
    for (int c = 0; c < 64; ++c) {
        float xv[4], wv[4];
        #pragma unroll
        for (int j = 0; j < 4; ++j) { xv[j] = lx[c][v0+j]; wv[j] = lwa[o0+j][c]; }
        #pragma unroll
        for (int vj = 0; vj < 4; ++vj)
            #pragma unroll
            for (int oj = 0; oj < 4; ++oj)
                acc[vj][oj] = fmaf(xv[vj], wv[oj], acc[vj][oj]);
    }
    #pragma unroll
    for (int vj = 0; vj < 4; ++vj) {
        float4 r = make_float4(acc[vj][0], acc[vj][1], acc[vj][2], acc[vj][3]);
        *(float4*)&pre[((size_t)(n*S_ + s0 + v0 + vj))*64 + o0] = r;
    }
    __syncthreads();   // done reading lx as [c][v]
    #pragma unroll
    for (int vj = 0; vj < 4; ++vj)
        #pragma unroll
        for (int oj = 0; oj < 4; ++oj)
            lx[v0+vj][o0+oj] = acc[vj][oj];   // now lx = pre tile [v][c2]
    __syncthreads();
    float acc2[4][4];
    #pragma unroll
    for (int oj = 0; oj < 4; ++oj) {
        float bo = b_in[o0+oj];
        #pragma unroll
        for (int vj = 0; vj < 4; ++vj) acc2[vj][oj] = bo;
    }
    #pragma unroll 8
    for (int c = 0; c < 64; ++c) {
        float fv[4], wv[4];
        #pragma unroll
        for (int j = 0; j < 4; ++j) { fv[j] = lx[v0+j][c]; wv[j] = lwb[c][o0+j]; }
        #pragma unroll
        for (int vj = 0; vj < 4; ++vj)
            #pragma unroll
            for (int oj = 0; oj < 4; ++oj)
                acc2[vj][oj] = fmaf(fv[vj], wv[oj], acc2[vj][oj]);
    }
    #pragma unroll
    for (int vj = 0; vj < 4; ++vj) {
        int vox = s0 + v0 + vj;      // within image n
        int z = vox / HW_;
        int rem = vox - z*HW_;
        int y = rem / W_;
        int xq = rem - y*W_;
        size_t pw = (size_t)n*NSTR_ + (size_t)(z+2)*ZS_ + (y+2)*YS_ + (xq+2)*64 + o0;
        float4 r = make_float4(acc2[vj][0], acc2[vj][1], acc2[vj][2], acc2[vj][3]);
        *(float4*)&xprojP[pw] = r;
    }
}

// depthwise 3x3x3 + instance-norm partials; 4 channels per thread, float4 loads
__global__ __launch_bounds__(256) void k_dw_stats(const float* __restrict__ pre,
        const float* __restrict__ w_dw, float* __restrict__ dw,
        float* __restrict__ psum, float* __restrict__ pss) {
    __shared__ float4 lwd[27][16];     // [tap][c4]
    __shared__ float4 lsum[16][16];    // [xg][c4]
    __shared__ float4 lssum[16][16];
    int b = blockIdx.x;               // n*D*H + z*H + y  (1536)
    int y = b % H_;
    int z = (b / H_) % D_;
    int n = b / (D_*H_);
    int tid = threadIdx.x;
    if (tid < 27*16) {
        int k = tid >> 4, c4 = tid & 15;
        lwd[k][c4] = make_float4(w_dw[(c4*4+0)*27 + k], w_dw[(c4*4+1)*27 + k],
                                 w_dw[(c4*4+2)*27 + k], w_dw[(c4*4+3)*27 + k]);
    }
    __syncthreads();
    int c4 = tid & 15, xg = tid >> 4;
    const float* preN = pre + (size_t)n*S_*64;
    float4 s4 = make_float4(0,0,0,0), ss4 = make_float4(0,0,0,0);
    for (int xx = 0; xx < 6; ++xx) {
        int xi = xg + xx*16;
        float4 acc = make_float4(0,0,0,0);
        #pragma unroll
        for (int dz = 0; dz < 3; ++dz) {
            int zz = z + dz - 1;
            if (zz < 0 || zz >= D_) continue;
            #pragma unroll
            for (int dy = 0; dy < 3; ++dy) {
                int yy = y + dy - 1;
                if (yy < 0 || yy >= H_) continue;
                int rowb = (zz*HW_ + yy*W_)*64 + c4*4;
                #pragma unroll
                for (int dx = 0; dx < 3; ++dx) {
                    int xn = xi + dx - 1;
                    if ((unsigned)xn < (unsigned)W_) {
                        float4 v = *(const float4*)&preN[rowb + (xn<<6)];
                        float4 w = lwd[dz*9+dy*3+dx][c4];
                        acc.x = fmaf(v.x, w.x, acc.x);
                        acc.y = fmaf(v.y, w.y, acc.y);
                        acc.z = fmaf(v.z, w.z, acc.z);
                        acc.w = fmaf(v.w, w.w, acc.w);
                    }
                }
            }
        }
        *(float4*)&dw[((size_t)n*S_ + z*HW_ + y*W_ + xi)*64 + c4*4] = acc;
        s4.x += acc.x; s4.y += acc.y; s4.z += acc.z; s4.w += acc.w;
        ss4.x = fmaf(acc.x, acc.x, ss4.x); ss4.y = fmaf(acc.y, acc.y, ss4.y);
        ss4.z = fmaf(acc.z, acc.z, ss4.z); ss4.w = fmaf(acc.w, acc.w, ss4.w);
    }
    lsum[xg][c4] = s4; lssum[xg][c4] = ss4;
    __syncthreads();
    if (tid < 64) {
        float s = 0.f, ss = 0.f;
        #pragma unroll
        for (int k = 0; k < 16; ++k) {
            s  += ((const float*)&lsum [k][tid>>2])[tid&3];
            ss += ((const float*)&lssum[k][tid>>2])[tid&3];
        }
        psum[tid*1536 + b] = s;
        pss [tid*1536 + b] = ss;
    }
}

// reduce partials -> mean / rsqrt(var)
__global__ void k_stats2(const float* __restrict__ psum, const float* __restrict__ pss,
                         float* __restrict__ stats) {
    int u = blockIdx.x;               // 0..127
    int n = u >> 6, c = u & 63;
    int l = threadIdx.x;              // 0..63
    float s = 0.f, ss = 0.f;
    #pragma unroll
    for (int k = 0; k < 12; ++k) {
        int row = n*768 + k*64 + l;
        s  += psum[c*1536 + row];
        ss += pss [c*1536 + row];
    }
    #pragma unroll
    for (int o2 = 32; o2 >= 1; o2 >>= 1) {
        s  += __shfl_xor(s, o2);
        ss += __shfl_xor(ss, o2);
    }
    if (l == 0) {
        float inv = 1.f / (float)S_;
        float mean = s * inv;
        float var = ss * inv - mean*mean;
        stats[n*128 + c] = mean;
        stats[n*128 + 64 + c] = rsqrtf(var + 1e-5f);
    }
}

// fused DCN: block = 1z x 4y x 4x voxel tile; XCD-chunked block swizzle.
__global__ __launch_bounds__(256) void k_dcn(const float* __restrict__ xprojP,
        const float* __restrict__ dw, const float* __restrict__ stats,
        const float4* __restrict__ woffT4, const float4* __restrict__ b4f,
        float* __restrict__ core) {
    __shared__ float featT[64][20];     // [c][vox]
    __shared__ float4 offs4[32][33];    // [pair][tap]: dx,dy,dz, logit->prob
    int tid = threadIdx.x;
    // bijective XCD swizzle: 9216 blocks = 8 * 1152
    int orig = blockIdx.x;
    int bid = (orig & 7) * 1152 + (orig >> 3);
    int x4 = bid % 24;
    int t1 = bid / 24;
    int y4 = t1 % 24;
    int t2 = t1 / 24;                 // 0..15
    int z  = t2 & 7;
    int n  = t2 >> 3;
    int yb = y4*4, xb = x4*4;
    size_t voxBase = (size_t)n*S_ + (size_t)z*HW_ + yb*W_ + xb;

    // 1a: feat = gelu(instnorm(dw)) transposed into LDS
    {
        int vi = tid >> 4, c4 = (tid & 15) * 4;
        size_t vox = voxBase + (vi>>2)*W_ + (vi & 3);
        float4 v = *(const float4*)&dw[vox*64 + c4];
        float vals[4] = {v.x, v.y, v.z, v.w};
        #pragma unroll
        for (int j = 0; j < 4; ++j) {
            int c = c4 + j;
            float t = (vals[j] - stats[n*128+c]) * stats[n*128+64+c];
            featT[c][vi] = gelu_fast(t);
        }
    }
    __syncthreads();

    // 1b: offset/mask projection; thread = (u=(g,p), 4-voxel quad)
    if (tid < 216) {
        int vi4 = tid / 54;
        int u = tid - vi4*54;
        int g = u / 27, p = u - g*27;
        float4 bb = b4f[u];
        float4 a0 = bb, a1 = bb, a2 = bb, a3 = bb;
        for (int c = 0; c < 64; ++c) {
            float4 w = woffT4[c*64 + u];
            float4 f = *(const float4*)&featT[c][vi4*4];
            a0.x = fmaf(f.x, w.x, a0.x); a0.y = fmaf(f.x, w.y, a0.y);
            a0.z = fmaf(f.x, w.z, a0.z); a0.w = fmaf(f.x, w.w, a0.w);
            a1.x = fmaf(f.y, w.x, a1.x); a1.y = fmaf(f.y, w.y, a1.y);
            a1.z = fmaf(f.y, w.z, a1.z); a1.w = fmaf(f.y, w.w, a1.w);
            a2.x = fmaf(f.z, w.x, a2.x); a2.y = fmaf(f.z, w.y, a2.y);
            a2.z = fmaf(f.z, w.z, a2.z); a2.w = fmaf(f.z, w.w, a2.w);
            a3.x = fmaf(f.w, w.x, a3.x); a3.y = fmaf(f.w, w.y, a3.y);
            a3.z = fmaf(f.w, w.z, a3.z); a3.w = fmaf(f.w, w.w, a3.w);
        }
        offs4[(vi4*4+0)*2+g][p] = a0;
        offs4[(vi4*4+1)*2+g][p] = a1;
        offs4[(vi4*4+2)*2+g][p] = a2;
        offs4[(vi4*4+3)*2+g][p] = a3;
    }
    __syncthreads();

    // softmax over taps per pair
    if (tid < 32) {
        float mx = -1e30f;
        #pragma unroll
        for (int p = 0; p < 27; ++p) mx = fmaxf(mx, offs4[tid][p].w);
        float e[27]; float ssum = 0.f;
        #pragma unroll
        for (int p = 0; p < 27; ++p) { e[p] = __expf(offs4[tid][p].w - mx); ssum += e[p]; }
        float inv = __builtin_amdgcn_rcpf(ssum);
        #pragma unroll
        for (int p = 0; p < 27; ++p) offs4[tid][p].w = e[p]*inv;
    }
    __syncthreads();

    // phase 2: 8 lanes x float4 channels per (voxel, g); zero pad ring -> no bounds tests
    int lane = tid & 63;
    int pl = (tid >> 6)*8 + (lane >> 3);
    int vloc = pl >> 1, g = pl & 1;
    int yy = vloc >> 2, xx = vloc & 3;
    int yv = yb + yy, xv = xb + xx;
    const float* __restrict__ base = xprojP + (size_t)n*NSTR_;   // block-uniform
    int Kc = 2*ZS_ + 2*YS_ + 128 + g*32 + (lane & 7)*4;          // pad + lane offset, words
    float fzb = (float)(z-1), fyb = (float)(yv-1), fxb = (float)(xv-1);
    float a0 = 0.f, a1 = 0.f, a2 = 0.f, a3 = 0.f;
    #pragma unroll
    for (int p = 0; p < 27; ++p) {
        float4 tp = offs4[pl][p];
        float zf = fzb + (float)(p/9) + tp.z;
        float yf = fyb + (float)((p/3)%3) + tp.y;
        float xf = fxb + (float)(p%3) + tp.x;
        zf = fminf(fmaxf(zf, -1.5f), (float)D_ + 0.5f);
        yf = fminf(fmaxf(yf, -1.5f), (float)H_ + 0.5f);
        xf = fminf(fmaxf(xf, -1.5f), (float)W_ + 0.5f);
        float z0f = floorf(zf), y0f = floorf(yf), x0f = floorf(xf);
        float fz = zf - z0f, fy = yf - y0f, fx = xf - x0f;
        int zi = (int)z0f, yi = (int)y0f, xi = (int)x0f;
        float wz1 = fz * tp.w, wz0 = tp.w - wz1;    // prob folded into z-weights
        float wy1 = fy, wy0 = 1.f - fy;
        float wx1 = fx, wx0 = 1.f - fx;
        float w00 = wz0*wy0, w01 = wz0*wy1, w10 = wz1*wy0, w11 = wz1*wy1;
        float c000 = w00*wx0, c001 = w00*wx1, c010 = w01*wx0, c011 = w01*wx1;
        float c100 = w10*wx0, c101 = w10*wx1, c110 = w11*wx0, c111 = w11*wx1;
        int cw = zi*ZS_ + yi*YS_ + (xi << 6) + Kc;   // 32-bit word offset, >= 0
        const float* p00 = base + cw;
        const float* p01 = p00 + YS_;
        const float* p10 = p00 + ZS_;
        const float* p11 = p10 + YS_;
        float4 v000 = *(const float4*)p00;
        float4 v001 = *(const float4*)(p00 + 64);
        float4 v010 = *(const float4*)p01;
        float4 v011 = *(const float4*)(p01 + 64);
        float4 v100 = *(const float4*)p10;
        float4 v101 = *(const float4*)(p10 + 64);
        float4 v110 = *(const float4*)p11;
        float4 v111 = *(const float4*)(p11 + 64);
        a0 = fmaf(c000, v000.x, a0); a1 = fmaf(c000, v000.y, a1);
        a2 = fmaf(c000, v000.z, a2); a3 = fmaf(c000, v000.w, a3);
        a0 = fmaf(c001, v001.x, a0); a1 = fmaf(c001, v001.y, a1);
        a2 = fmaf(c001, v001.z, a2); a3 = fmaf(c001, v001.w, a3);
        a0 = fmaf(c010, v010.x, a0); a1 = fmaf(c010, v010.y, a1);
        a2 = fmaf(c010, v010.z, a2); a3 = fmaf(c010, v010.w, a3);
        a0 = fmaf(c011, v011.x, a0); a1 = fmaf(c011, v011.y, a1);
        a2 = fmaf(c011, v011.z, a2); a3 = fmaf(c011, v011.w, a3);
        a0 = fmaf(c100, v100.x, a0); a1 = fmaf(c100, v100.y, a1);
        a2 = fmaf(c100, v100.z, a2); a3 = fmaf(c100, v100.w, a3);
        a0 = fmaf(c101, v101.x, a0); a1 = fmaf(c101, v101.y, a1);
        a2 = fmaf(c101, v101.z, a2); a3 = fmaf(c101, v101.w, a3);
        a0 = fmaf(c110, v110.x, a0); a1 = fmaf(c110, v110.y, a1);
        a2 = fmaf(c110, v110.z, a2); a3 = fmaf(c110, v110.w, a3);
        a0 = fmaf(c111, v111.x, a0); a1 = fmaf(c111, v111.y, a1);
        a2 = fmaf(c111, v111.z, a2); a3 = fmaf(c111, v111.w, a3);
    }
    float4 r = make_float4(a0, a1, a2, a3);
    size_t voxOut = voxBase + yy*W_ + xx;
    *(float4*)&core[voxOut*64 + g*32 + (lane & 7)*4] = r;
}

// out = x + sigmoid(gate) * (core @ W2 + B2), back to NCDHW
__global__ __launch_bounds__(256) void k_final(const float* __restrict__ core,
        const float* __restrict__ W2, const float* __restrict__ B2,
        const float* __restrict__ x, const float* __restrict__ gate,
        float* __restrict__ out) {
    __shared__ float lc[64][65];   // [v][c]
    __shared__ float lw[64][65];   // [c][o]
    int b = blockIdx.x;
    int n = b / 1152;
    int s0 = (b % 1152) * 64;
    int tid = threadIdx.x;
    for (int idx = tid; idx < 1024; idx += 256) {
        int r = idx >> 4, q4 = (idx & 15) * 4;
        float4 vc = *(const float4*)&core[((size_t)(n*S_ + s0 + r))*64 + q4];
        lc[r][q4] = vc.x; lc[r][q4+1] = vc.y; lc[r][q4+2] = vc.z; lc[r][q4+3] = vc.w;
        float4 vw = *(const float4*)&W2[r*64 + q4];
        lw[r][q4] = vw.x; lw[r][q4+1] = vw.y; lw[r][q4+2] = vw.z; lw[r][q4+3] = vw.w;
    }
    __syncthreads();
    float sg = 1.f / (1.f + expf(-gate[0]));
    int o0 = (tid & 15) * 4;
    int v0 = (tid >> 4) * 4;
    float acc[4][4];
    #pragma unroll
    for (int oj = 0; oj < 4; ++oj) {
        float bo = B2[o0+oj];
        #pragma unroll
        for (int vj = 0; vj < 4; ++vj) acc[vj][oj] = bo;
    }
    #pragma unroll 8
    for (int c = 0; c < 64; ++c) {
        float fv[4], wv[4];
        #pragma unroll
        for (int j = 0; j < 4; ++j) { fv[j] = lc[v0+j][c]; wv[j] = lw[c][o0+j]; }
        #pragma unroll
        for (int vj = 0; vj < 4; ++vj)
            #pragma unroll
            for (int oj = 0; oj < 4; ++oj)
                acc[vj][oj] = fmaf(fv[vj], wv[oj], acc[vj][oj]);
    }
    #pragma unroll
    for (int oj = 0; oj < 4; ++oj) {
        size_t gi = ((size_t)(n*64 + o0 + oj))*S_ + s0 + v0;
        float4 xv = *(const float4*)&x[gi];
        float4 r;
        r.x = fmaf(sg, acc[0][oj], xv.x);
        r.y = fmaf(sg, acc[1][oj], xv.y);
        r.z = fmaf(sg, acc[2][oj], xv.z);
        r.w = fmaf(sg, acc[3][oj], xv.w);
        *(float4*)&out[gi] = r;
    }
}

extern "C" void kernel_launch(void* const* d_in, const int* in_sizes, int n_in,
                              void* d_out, int out_size, void* d_ws, size_t ws_size,
                              hipStream_t stream) {
    const float* x      = (const float*)d_in[0];
    const float* w_pre  = (const float*)d_in[1];
    const float* w_in   = (const float*)d_in[2];
    const float* b_in   = (const float*)d_in[3];
    const float* w_dw   = (const float*)d_in[4];
    const float* w_off  = (const float*)d_in[5];
    const float* b_off  = (const float*)d_in[6];
    const float* w_mask = (const float*)d_in[7];
    const float* b_mask = (const float*)d_in[8];
    const float* w_out  = (const float*)d_in[9];
    const float* b_out  = (const float*)d_in[10];
    const float* w_post = (const float*)d_in[11];
    const float* gate   = (const float*)d_in[12];
    float* out = (float*)d_out;

    float* ws      = (float*)d_ws;
    float* xprojP  = ws;                               // 15,360,000
    float* preCore = xprojP + (size_t)15360000;        // 9,437,184 (pre, then core)
    float* psum    = preCore + (size_t)9437184;        // 98,304
    float* pss     = psum + 98304;                     // 98,304
    float* stats   = pss + 98304;                      // 256
    float* W2      = stats + 256;                      // 4,096
    float* B2      = W2 + 4096;                        // 64 (+pad)
    float4* woffT4 = (float4*)(B2 + 128);              // 64*64 float4
    float4* b4f    = woffT4 + 4096;                    // 54 float4 (+pad)
    float* dwb     = out;                              // d_out doubles as dw scratch

    hipMemsetAsync(xprojP, 0, (size_t)15360000*4, stream);
    hipLaunchKernelGGL(k_prep,     dim3(64),   dim3(64),  0, stream,
                       w_out, b_out, w_post, w_off, b_off, w_mask, b_mask,
                       W2, B2, woffT4, b4f);
    hipLaunchKernelGGL(k_pre_proj, dim3(2304), dim3(256), 0, stream,
                       x, w_pre, w_in, b_in, preCore, xprojP);
    hipLaunchKernelGGL(k_dw_stats, dim3(1536), dim3(256), 0, stream,
                       preCore, w_dw, dwb, psum, pss);
    hipLaunchKernelGGL(k_stats2,   dim3(128),  dim3(64),  0, stream, psum, pss, stats);
    hipLaunchKernelGGL(k_dcn,      dim3(9216), dim3(256), 0, stream,
                       xprojP, dwb, stats, woffT4, b4f, preCore);
    hipLaunchKernelGGL(k_final,    dim3(2304), dim3(256), 0, stream,
                       preCore, W2, B2, x, gate, out);
}

// Round 5
// 340.776 us; speedup vs baseline: 2.9934x; 1.3157x over previous
//
#include <hip/hip_runtime.h>
#include <math.h>

#define N_ 2
#define C_ 64
#define D_ 8
#define H_ 96
#define W_ 96
#define S_ (D_*H_*W_)   // 73728
#define HW_ (H_*W_)     // 9216
// padded xproj (bf16): [n][z+2 of 12][y+2 of 100][x+2 of 100][64]
#define ZP_ 12
#define YP_ 100
#define XP_ 100
#define NSTR_ (ZP_*YP_*XP_*64)   // 7680000 elements
#define ZS_ (YP_*XP_*64)         // 640000
#define YS_ (XP_*64)             // 6400

__device__ __forceinline__ float gelu_fast(float x) {
    // 0.5x(1+tanh(a)) = x - x/(exp(2a)+1)
    float a = 0.7978845608028654f * (x + 0.044715f*x*x*x);
    float E = __expf(2.f*a);
    return x - x * __builtin_amdgcn_rcpf(E + 1.f);
}

__device__ __forceinline__ unsigned short f2bf(float f) {   // RNE bf16
    unsigned u = __float_as_uint(f);
    unsigned r = (u + 0x7fffu + ((u >> 16) & 1u)) >> 16;
    return (unsigned short)r;
}

// prep: W2 = w_out @ w_post^T folded, B2, woffT[c][u] float4 (AXIS_SCALE folded), b4[u]
__global__ __launch_bounds__(64) void k_prep(const float* __restrict__ w_out,
        const float* __restrict__ b_out, const float* __restrict__ w_post,
        const float* __restrict__ w_off, const float* __restrict__ b_off,
        const float* __restrict__ w_mask, const float* __restrict__ b_mask,
        float* __restrict__ W2, float* __restrict__ B2,
        float4* __restrict__ woffT4, float4* __restrict__ b4f) {
    int b = blockIdx.x;      // 0..63
    int t = threadIdx.x;     // 0..63
    float acc = 0.f;
    for (int c = 0; c < 64; ++c)
        acc = fmaf(w_out[b*64+c], w_post[t*64+c], acc);
    W2[b*64 + t] = acc;
    if (b == 0) {
        float a2 = 0.f;
        for (int c = 0; c < 64; ++c)
            a2 = fmaf(w_post[t*64+c], b_out[c], a2);
        B2[t] = a2;
    }
    if (t < 54) {
        int c = b, u = t;
        woffT4[c*64 + u] = make_float4(w_off[c*162 + u*3] * 0.5f,
                                       w_off[c*162 + u*3 + 1],
                                       w_off[c*162 + u*3 + 2],
                                       w_mask[c*54 + u]);
        if (b == 1)
            b4f[u] = make_float4(b_off[u*3] * 0.5f, b_off[u*3+1], b_off[u*3+2],
                                 b_mask[u]);
    }
}

// fused: pre = x @ w_pre^T (fp32, for dw), xprojP = bf16(pre @ w_in + b_in) padded
__global__ __launch_bounds__(256) void k_pre_proj(const float* __restrict__ x,
        const float* __restrict__ w_pre, const float* __restrict__ w_in,
        const float* __restrict__ b_in, float* __restrict__ pre,
        unsigned short* __restrict__ xprojP) {
    __shared__ float lx[64][65];    // [c][v] then reused as [v][c2]
    __shared__ float lwa[64][65];   // w_pre [o][c]
    __shared__ float lwb[64][65];   // w_in  [c][o]
    int b = blockIdx.x;
    int n = b / 1152;
    int s0 = (b % 1152) * 64;
    int tid = threadIdx.x;
    for (int idx = tid; idx < 1024; idx += 256) {
        int r = idx >> 4, q4 = (idx & 15) * 4;
        float4 vx = *(const float4*)&x[((size_t)(n*C_ + r))*S_ + s0 + q4];
        lx[r][q4] = vx.x; lx[r][q4+1] = vx.y; lx[r][q4+2] = vx.z; lx[r][q4+3] = vx.w;
        float4 va = *(const float4*)&w_pre[r*64 + q4];
        lwa[r][q4] = va.x; lwa[r][q4+1] = va.y; lwa[r][q4+2] = va.z; lwa[r][q4+3] = va.w;
        float4 vb = *(const float4*)&w_in[r*64 + q4];
        lwb[r][q4] = vb.x; lwb[r][q4+1] = vb.y; lwb[r][q4+2] = vb.z; lwb[r][q4+3] = vb.w;
    }
    __syncthreads();
    int o0 = (tid & 15) * 4;
    int v0 = (tid >> 4) * 4;
    float acc[4][4] = {};
    #pragma unroll 8
    for (int c = 0; c < 64; ++c) {
        float xv[4], wv[4];
        #pragma unroll
        for (int j = 0; j < 4; ++j) { xv[j] = lx[c][v0+j]; wv[j] = lwa[o0+j][c]; }
        #pragma unroll
        for (int vj = 0; vj < 4; ++vj)
            #pragma unroll
            for (int oj = 0; oj < 4; ++oj)
                acc[vj][oj] = fmaf(xv[vj], wv[oj], acc[vj][oj]);
    }
    #pragma unroll
    for (int vj = 0; vj < 4; ++vj) {
        float4 r = make_float4(acc[vj][0], acc[vj][1], acc[vj][2], acc[vj][3]);
        *(float4*)&pre[((size_t)(n*S_ + s0 + v0 + vj))*64 + o0] = r;
    }
    __syncthreads();   // done reading lx as [c][v]
    #pragma unroll
    for (int vj = 0; vj < 4; ++vj)
        #pragma unroll
        for (int oj = 0; oj < 4; ++oj)
            lx[v0+vj][o0+oj] = acc[vj][oj];   // now lx = pre tile [v][c2]
    __syncthreads();
    float acc2[4][4];
    #pragma unroll
    for (int oj = 0; oj < 4; ++oj) {
        float bo = b_in[o0+oj];
        #pragma unroll
        for (int vj = 0; vj < 4; ++vj) acc2[vj][oj] = bo;
    }
    #pragma unroll 8
    for (int c = 0; c < 64; ++c) {
        float fv[4], wv[4];
        #pragma unroll
        for (int j = 0; j < 4; ++j) { fv[j] = lx[v0+j][c]; wv[j] = lwb[c][o0+j]; }
        #pragma unroll
        for (int vj = 0; vj < 4; ++vj)
            #pragma unroll
            for (int oj = 0; oj < 4; ++oj)
                acc2[vj][oj] = fmaf(fv[vj], wv[oj], acc2[vj][oj]);
    }
    #pragma unroll
    for (int vj = 0; vj < 4; ++vj) {
        int vox = s0 + v0 + vj;      // within image n
        int z = vox / HW_;
        int rem = vox - z*HW_;
        int y = rem / W_;
        int xq = rem - y*W_;
        size_t pw = (size_t)n*NSTR_ + (size_t)(z+2)*ZS_ + (y+2)*YS_ + (xq+2)*64 + o0;
        ushort4 pk;
        pk.x = f2bf(acc2[vj][0]); pk.y = f2bf(acc2[vj][1]);
        pk.z = f2bf(acc2[vj][2]); pk.w = f2bf(acc2[vj][3]);
        *(ushort4*)&xprojP[pw] = pk;
    }
}

// depthwise 3x3x3 + instance-norm partials; 4 channels per thread, float4 loads
__global__ __launch_bounds__(256) void k_dw_stats(const float* __restrict__ pre,
        const float* __restrict__ w_dw, float* __restrict__ dw,
        float* __restrict__ psum, float* __restrict__ pss) {
    __shared__ float4 lwd[27][16];     // [tap][c4]
    __shared__ float4 lsum[16][16];    // [xg][c4]
    __shared__ float4 lssum[16][16];
    int b = blockIdx.x;               // n*D*H + z*H + y  (1536)
    int y = b % H_;
    int z = (b / H_) % D_;
    int n = b / (D_*H_);
    int tid = threadIdx.x;
    if (tid < 27*16) {
        int k = tid >> 4, c4 = tid & 15;
        lwd[k][c4] = make_float4(w_dw[(c4*4+0)*27 + k], w_dw[(c4*4+1)*27 + k],
                                 w_dw[(c4*4+2)*27 + k], w_dw[(c4*4+3)*27 + k]);
    }
    __syncthreads();
    int c4 = tid & 15, xg = tid >> 4;
    const float* preN = pre + (size_t)n*S_*64;
    float4 s4 = make_float4(0,0,0,0), ss4 = make_float4(0,0,0,0);
    for (int xx = 0; xx < 6; ++xx) {
        int xi = xg + xx*16;
        float4 acc = make_float4(0,0,0,0);
        #pragma unroll
        for (int dz = 0; dz < 3; ++dz) {
            int zz = z + dz - 1;
            if (zz < 0 || zz >= D_) continue;
            #pragma unroll
            for (int dy = 0; dy < 3; ++dy) {
                int yy = y + dy - 1;
                if (yy < 0 || yy >= H_) continue;
                int rowb = (zz*HW_ + yy*W_)*64 + c4*4;
                #pragma unroll
                for (int dx = 0; dx < 3; ++dx) {
                    int xn = xi + dx - 1;
                    if ((unsigned)xn < (unsigned)W_) {
                        float4 v = *(const float4*)&preN[rowb + (xn<<6)];
                        float4 w = lwd[dz*9+dy*3+dx][c4];
                        acc.x = fmaf(v.x, w.x, acc.x);
                        acc.y = fmaf(v.y, w.y, acc.y);
                        acc.z = fmaf(v.z, w.z, acc.z);
                        acc.w = fmaf(v.w, w.w, acc.w);
                    }
                }
            }
        }
        *(float4*)&dw[((size_t)n*S_ + z*HW_ + y*W_ + xi)*64 + c4*4] = acc;
        s4.x += acc.x; s4.y += acc.y; s4.z += acc.z; s4.w += acc.w;
        ss4.x = fmaf(acc.x, acc.x, ss4.x); ss4.y = fmaf(acc.y, acc.y, ss4.y);
        ss4.z = fmaf(acc.z, acc.z, ss4.z); ss4.w = fmaf(acc.w, acc.w, ss4.w);
    }
    lsum[xg][c4] = s4; lssum[xg][c4] = ss4;
    __syncthreads();
    if (tid < 64) {
        float s = 0.f, ss = 0.f;
        #pragma unroll
        for (int k = 0; k < 16; ++k) {
            s  += ((const float*)&lsum [k][tid>>2])[tid&3];
            ss += ((const float*)&lssum[k][tid>>2])[tid&3];
        }
        psum[tid*1536 + b] = s;
        pss [tid*1536 + b] = ss;
    }
}

// reduce partials -> mean / rsqrt(var)
__global__ void k_stats2(const float* __restrict__ psum, const float* __restrict__ pss,
                         float* __restrict__ stats) {
    int u = blockIdx.x;               // 0..127
    int n = u >> 6, c = u & 63;
    int l = threadIdx.x;              // 0..63
    float s = 0.f, ss = 0.f;
    #pragma unroll
    for (int k = 0; k < 12; ++k) {
        int row = n*768 + k*64 + l;
        s  += psum[c*1536 + row];
        ss += pss [c*1536 + row];
    }
    #pragma unroll
    for (int o2 = 32; o2 >= 1; o2 >>= 1) {
        s  += __shfl_xor(s, o2);
        ss += __shfl_xor(ss, o2);
    }
    if (l == 0) {
        float inv = 1.f / (float)S_;
        float mean = s * inv;
        float var = ss * inv - mean*mean;
        stats[n*128 + c] = mean;
        stats[n*128 + 64 + c] = rsqrtf(var + 1e-5f);
    }
}

// fused DCN: block = 1z x 4y x 8x = 32 voxels (64 pairs); 4 lanes/pair, bf16 gather.
__global__ __launch_bounds__(256) void k_dcn(const unsigned short* __restrict__ xprojP,
        const float* __restrict__ dw, const float* __restrict__ stats,
        const float4* __restrict__ woffT4, const float4* __restrict__ b4f,
        float* __restrict__ core) {
    __shared__ float featT[64][36];     // [c][vox 0..31]
    __shared__ float4 offs4[64][29];    // [pair][tap]: dx,dy,dz, logit->prob
    int tid = threadIdx.x;
    // bijective XCD swizzle: 4608 blocks = 8 * 576
    int orig = blockIdx.x;
    int bid = (orig & 7) * 576 + (orig >> 3);
    int x8 = bid % 12;
    int t1 = bid / 12;
    int y4 = t1 % 24;
    int t2 = t1 / 24;                 // 0..15
    int z  = t2 & 7;
    int n  = t2 >> 3;
    int yb = y4*4, xb = x8*8;
    size_t voxBase = (size_t)n*S_ + (size_t)z*HW_ + yb*W_ + xb;

    // 1a: feat = gelu(instnorm(dw)) transposed into LDS (2 voxels x 4ch per thread)
    {
        int c4 = (tid & 15) * 4;
        int vp = tid >> 4;
        #pragma unroll
        for (int j = 0; j < 2; ++j) {
            int vloc = vp*2 + j;
            size_t vox = voxBase + (vloc>>3)*W_ + (vloc & 7);
            float4 v = *(const float4*)&dw[vox*64 + c4];
            float vals[4] = {v.x, v.y, v.z, v.w};
            #pragma unroll
            for (int jj = 0; jj < 4; ++jj) {
                int c = c4 + jj;
                float t = (vals[jj] - stats[n*128+c]) * stats[n*128+64+c];
                featT[c][vloc] = gelu_fast(t);
            }
        }
    }
    __syncthreads();

    // 1b: offset/mask projection; thread = (u=(g,p), 8-voxel octet)
    if (tid < 216) {
        int q = tid / 54;             // 0..3 -> voxels q*8..q*8+7
        int u = tid - q*54;
        int g = u / 27, p = u - g*27;
        float4 bb = b4f[u];
        float4 aa[8];
        #pragma unroll
        for (int j = 0; j < 8; ++j) aa[j] = bb;
        for (int c = 0; c < 64; ++c) {
            float4 w = woffT4[c*64 + u];
            float4 f0 = *(const float4*)&featT[c][q*8];
            float4 f1 = *(const float4*)&featT[c][q*8 + 4];
            float ff[8] = {f0.x, f0.y, f0.z, f0.w, f1.x, f1.y, f1.z, f1.w};
            #pragma unroll
            for (int j = 0; j < 8; ++j) {
                aa[j].x = fmaf(ff[j], w.x, aa[j].x);
                aa[j].y = fmaf(ff[j], w.y, aa[j].y);
                aa[j].z = fmaf(ff[j], w.z, aa[j].z);
                aa[j].w = fmaf(ff[j], w.w, aa[j].w);
            }
        }
        #pragma unroll
        for (int j = 0; j < 8; ++j)
            offs4[(q*8+j)*2 + g][p] = aa[j];
    }
    __syncthreads();

    // softmax over taps per pair (64 pairs)
    if (tid < 64) {
        float mx = -1e30f;
        #pragma unroll
        for (int p = 0; p < 27; ++p) mx = fmaxf(mx, offs4[tid][p].w);
        float e[27]; float ssum = 0.f;
        #pragma unroll
        for (int p = 0; p < 27; ++p) { e[p] = __expf(offs4[tid][p].w - mx); ssum += e[p]; }
        float inv = __builtin_amdgcn_rcpf(ssum);
        #pragma unroll
        for (int p = 0; p < 27; ++p) offs4[tid][p].w = e[p]*inv;
    }
    __syncthreads();

    // phase 2: 4 lanes x 8 bf16 channels per (voxel, g); zero pad ring -> no bounds tests
    int pair = tid >> 2;              // 0..63
    int vloc = pair >> 1, g = pair & 1;
    int yy = vloc >> 3, xx = vloc & 7;
    int yv = yb + yy, xv = xb + xx;
    int ch4 = (tid & 3) * 8;          // channel offset within group
    const unsigned short* __restrict__ base = xprojP + (size_t)n*NSTR_;
    int Kc = 2*ZS_ + 2*YS_ + 128 + g*32 + ch4;      // element (ushort) offset
    float fzb = (float)(z-1), fyb = (float)(yv-1), fxb = (float)(xv-1);
    float a0=0.f,a1=0.f,a2=0.f,a3=0.f,a4=0.f,a5=0.f,a6=0.f,a7=0.f;
    #pragma unroll
    for (int p = 0; p < 27; ++p) {
        float4 tp = offs4[pair][p];
        float zf = fzb + (float)(p/9) + tp.z;
        float yf = fyb + (float)((p/3)%3) + tp.y;
        float xf = fxb + (float)(p%3) + tp.x;
        zf = fminf(fmaxf(zf, -1.5f), (float)D_ + 0.5f);
        yf = fminf(fmaxf(yf, -1.5f), (float)H_ + 0.5f);
        xf = fminf(fmaxf(xf, -1.5f), (float)W_ + 0.5f);
        float z0f = floorf(zf), y0f = floorf(yf), x0f = floorf(xf);
        float fz = zf - z0f, fy = yf - y0f, fx = xf - x0f;
        int zi = (int)z0f, yi = (int)y0f, xi = (int)x0f;
        float wz1 = fz * tp.w, wz0 = tp.w - wz1;    // prob folded into z-weights
        float wy1 = fy, wy0 = 1.f - fy;
        float wx1 = fx, wx0 = 1.f - fx;
        float w00 = wz0*wy0, w01 = wz0*wy1, w10 = wz1*wy0, w11 = wz1*wy1;
        float c000 = w00*wx0, c001 = w00*wx1, c010 = w01*wx0, c011 = w01*wx1;
        float c100 = w10*wx0, c101 = w10*wx1, c110 = w11*wx0, c111 = w11*wx1;
        int cw = zi*ZS_ + yi*YS_ + (xi << 6) + Kc;   // >= 0, 32-bit
        const unsigned short* p00 = base + cw;
        const unsigned short* p01 = p00 + YS_;
        const unsigned short* p10 = p00 + ZS_;
        const unsigned short* p11 = p10 + YS_;
        uint4 q000 = *(const uint4*)p00;
        uint4 q001 = *(const uint4*)(p00 + 64);
        uint4 q010 = *(const uint4*)p01;
        uint4 q011 = *(const uint4*)(p01 + 64);
        uint4 q100 = *(const uint4*)p10;
        uint4 q101 = *(const uint4*)(p10 + 64);
        uint4 q110 = *(const uint4*)p11;
        uint4 q111 = *(const uint4*)(p11 + 64);
        #define ACC8(Q, WGT) { \
            float wq = (WGT); \
            a0 = fmaf(wq, __uint_as_float((Q).x << 16), a0); \
            a1 = fmaf(wq, __uint_as_float((Q).x & 0xffff0000u), a1); \
            a2 = fmaf(wq, __uint_as_float((Q).y << 16), a2); \
            a3 = fmaf(wq, __uint_as_float((Q).y & 0xffff0000u), a3); \
            a4 = fmaf(wq, __uint_as_float((Q).z << 16), a4); \
            a5 = fmaf(wq, __uint_as_float((Q).z & 0xffff0000u), a5); \
            a6 = fmaf(wq, __uint_as_float((Q).w << 16), a6); \
            a7 = fmaf(wq, __uint_as_float((Q).w & 0xffff0000u), a7); \
        }
        ACC8(q000, c000); ACC8(q001, c001); ACC8(q010, c010); ACC8(q011, c011);
        ACC8(q100, c100); ACC8(q101, c101); ACC8(q110, c110); ACC8(q111, c111);
        #undef ACC8
    }
    size_t voxOut = voxBase + yy*W_ + xx;
    size_t ob = voxOut*64 + g*32 + ch4;
    *(float4*)&core[ob]     = make_float4(a0, a1, a2, a3);
    *(float4*)&core[ob + 4] = make_float4(a4, a5, a6, a7);
}

// out = x + sigmoid(gate) * (core @ W2 + B2), back to NCDHW
__global__ __launch_bounds__(256) void k_final(const float* __restrict__ core,
        const float* __restrict__ W2, const float* __restrict__ B2,
        const float* __restrict__ x, const float* __restrict__ gate,
        float* __restrict__ out) {
    __shared__ float lc[64][65];   // [v][c]
    __shared__ float lw[64][65];   // [c][o]
    int b = blockIdx.x;
    int n = b / 1152;
    int s0 = (b % 1152) * 64;
    int tid = threadIdx.x;
    for (int idx = tid; idx < 1024; idx += 256) {
        int r = idx >> 4, q4 = (idx & 15) * 4;
        float4 vc = *(const float4*)&core[((size_t)(n*S_ + s0 + r))*64 + q4];
        lc[r][q4] = vc.x; lc[r][q4+1] = vc.y; lc[r][q4+2] = vc.z; lc[r][q4+3] = vc.w;
        float4 vw = *(const float4*)&W2[r*64 + q4];
        lw[r][q4] = vw.x; lw[r][q4+1] = vw.y; lw[r][q4+2] = vw.z; lw[r][q4+3] = vw.w;
    }
    __syncthreads();
    float sg = 1.f / (1.f + expf(-gate[0]));
    int o0 = (tid & 15) * 4;
    int v0 = (tid >> 4) * 4;
    float acc[4][4];
    #pragma unroll
    for (int oj = 0; oj < 4; ++oj) {
        float bo = B2[o0+oj];
        #pragma unroll
        for (int vj = 0; vj < 4; ++vj) acc[vj][oj] = bo;
    }
    #pragma unroll 8
    for (int c = 0; c < 64; ++c) {
        float fv[4], wv[4];
        #pragma unroll
        for (int j = 0; j < 4; ++j) { fv[j] = lc[v0+j][c]; wv[j] = lw[c][o0+j]; }
        #pragma unroll
        for (int vj = 0; vj < 4; ++vj)
            #pragma unroll
            for (int oj = 0; oj < 4; ++oj)
                acc[vj][oj] = fmaf(fv[vj], wv[oj], acc[vj][oj]);
    }
    #pragma unroll
    for (int oj = 0; oj < 4; ++oj) {
        size_t gi = ((size_t)(n*64 + o0 + oj))*S_ + s0 + v0;
        float4 xv = *(const float4*)&x[gi];
        float4 r;
        r.x = fmaf(sg, acc[0][oj], xv.x);
        r.y = fmaf(sg, acc[1][oj], xv.y);
        r.z = fmaf(sg, acc[2][oj], xv.z);
        r.w = fmaf(sg, acc[3][oj], xv.w);
        *(float4*)&out[gi] = r;
    }
}

extern "C" void kernel_launch(void* const* d_in, const int* in_sizes, int n_in,
                              void* d_out, int out_size, void* d_ws, size_t ws_size,
                              hipStream_t stream) {
    const float* x      = (const float*)d_in[0];
    const float* w_pre  = (const float*)d_in[1];
    const float* w_in   = (const float*)d_in[2];
    const float* b_in   = (const float*)d_in[3];
    const float* w_dw   = (const float*)d_in[4];
    const float* w_off  = (const float*)d_in[5];
    const float* b_off  = (const float*)d_in[6];
    const float* w_mask = (const float*)d_in[7];
    const float* b_mask = (const float*)d_in[8];
    const float* w_out  = (const float*)d_in[9];
    const float* b_out  = (const float*)d_in[10];
    const float* w_post = (const float*)d_in[11];
    const float* gate   = (const float*)d_in[12];
    float* out = (float*)d_out;

    float* ws      = (float*)d_ws;
    unsigned short* xprojP = (unsigned short*)ws;      // 15,360,000 ushorts (30.72MB)
    float* preCore = ws + (size_t)7680000;             // 9,437,184 floats (pre, then core)
    float* psum    = preCore + (size_t)9437184;        // 98,304
    float* pss     = psum + 98304;                     // 98,304
    float* stats   = pss + 98304;                      // 256
    float* W2      = stats + 256;                      // 4,096
    float* B2      = W2 + 4096;                        // 64 (+pad)
    float4* woffT4 = (float4*)(B2 + 128);              // 64*64 float4
    float4* b4f    = woffT4 + 4096;                    // 54 float4 (+pad)
    float* dwb     = out;                              // d_out doubles as dw scratch

    hipMemsetAsync(xprojP, 0, (size_t)15360000*sizeof(unsigned short), stream);
    hipLaunchKernelGGL(k_prep,     dim3(64),   dim3(64),  0, stream,
                       w_out, b_out, w_post, w_off, b_off, w_mask, b_mask,
                       W2, B2, woffT4, b4f);
    hipLaunchKernelGGL(k_pre_proj, dim3(2304), dim3(256), 0, stream,
                       x, w_pre, w_in, b_in, preCore, xprojP);
    hipLaunchKernelGGL(k_dw_stats, dim3(1536), dim3(256), 0, stream,
                       preCore, w_dw, dwb, psum, pss);
    hipLaunchKernelGGL(k_stats2,   dim3(128),  dim3(64),  0, stream, psum, pss, stats);
    hipLaunchKernelGGL(k_dcn,      dim3(4608), dim3(256), 0, stream,
                       xprojP, dwb, stats, woffT4, b4f, preCore);
    hipLaunchKernelGGL(k_final,    dim3(2304), dim3(256), 0, stream,
                       preCore, W2, B2, x, gate, out);
}

// Round 6
// 329.360 us; speedup vs baseline: 3.0972x; 1.0347x over previous
//
#include <hip/hip_runtime.h>
#include <math.h>

#define N_ 2
#define C_ 64
#define D_ 8
#define H_ 96
#define W_ 96
#define S_ (D_*H_*W_)   // 73728
#define HW_ (H_*W_)     // 9216
// padded xproj (bf16): [n][z+2 of 12][y+2 of 100][x+2 of 100][64]
#define ZP_ 12
#define YP_ 100
#define XP_ 100
#define NSTR_ (ZP_*YP_*XP_*64)   // 7680000 elements
#define ZS_ (YP_*XP_*64)         // 640000
#define YS_ (XP_*64)             // 6400

__device__ __forceinline__ float gelu_fast(float x) {
    // 0.5x(1+tanh(a)) = x - x/(exp(2a)+1)
    float a = 0.7978845608028654f * (x + 0.044715f*x*x*x);
    float E = __expf(2.f*a);
    return x - x * __builtin_amdgcn_rcpf(E + 1.f);
}

__device__ __forceinline__ unsigned short f2bf(float f) {   // RNE bf16
    unsigned u = __float_as_uint(f);
    unsigned r = (u + 0x7fffu + ((u >> 16) & 1u)) >> 16;
    return (unsigned short)r;
}

// pack top-16 of two f32 into one uint: {hi16(a), hi16(b)}
__device__ __forceinline__ unsigned pkhi(float a, float b) {
    return __builtin_amdgcn_perm(__float_as_uint(a), __float_as_uint(b), 0x07060302u);
}

// prep: W2 = w_out @ w_post^T folded, B2, woffT[c][u] float4 (AXIS_SCALE folded), b4[u]
__global__ __launch_bounds__(64) void k_prep(const float* __restrict__ w_out,
        const float* __restrict__ b_out, const float* __restrict__ w_post,
        const float* __restrict__ w_off, const float* __restrict__ b_off,
        const float* __restrict__ w_mask, const float* __restrict__ b_mask,
        float* __restrict__ W2, float* __restrict__ B2,
        float4* __restrict__ woffT4, float4* __restrict__ b4f) {
    int b = blockIdx.x;      // 0..63
    int t = threadIdx.x;     // 0..63
    float acc = 0.f;
    for (int c = 0; c < 64; ++c)
        acc = fmaf(w_out[b*64+c], w_post[t*64+c], acc);
    W2[b*64 + t] = acc;
    if (b == 0) {
        float a2 = 0.f;
        for (int c = 0; c < 64; ++c)
            a2 = fmaf(w_post[t*64+c], b_out[c], a2);
        B2[t] = a2;
    }
    if (t < 54) {
        int c = b, u = t;
        woffT4[c*64 + u] = make_float4(w_off[c*162 + u*3] * 0.5f,
                                       w_off[c*162 + u*3 + 1],
                                       w_off[c*162 + u*3 + 2],
                                       w_mask[c*54 + u]);
        if (b == 1)
            b4f[u] = make_float4(b_off[u*3] * 0.5f, b_off[u*3+1], b_off[u*3+2],
                                 b_mask[u]);
    }
}

// fused: pre = x @ w_pre^T (fp32, for dw), xprojP = bf16(pre @ w_in + b_in) padded
__global__ __launch_bounds__(256) void k_pre_proj(const float* __restrict__ x,
        const float* __restrict__ w_pre, const float* __restrict__ w_in,
        const float* __restrict__ b_in, float* __restrict__ pre,
        unsigned short* __restrict__ xprojP) {
    __shared__ float lx[64][65];    // [c][v] then reused as [v][c2]
    __shared__ float lwa[64][65];   // w_pre [o][c]
    __shared__ float lwb[64][65];   // w_in  [c][o]
    int b = blockIdx.x;
    int n = b / 1152;
    int s0 = (b % 1152) * 64;
    int tid = threadIdx.x;
    for (int idx = tid; idx < 1024; idx += 256) {
        int r = idx >> 4, q4 = (idx & 15) * 4;
        float4 vx = *(const float4*)&x[((size_t)(n*C_ + r))*S_ + s0 + q4];
        lx[r][q4] = vx.x; lx[r][q4+1] = vx.y; lx[r][q4+2] = vx.z; lx[r][q4+3] = vx.w;
        float4 va = *(const float4*)&w_pre[r*64 + q4];
        lwa[r][q4] = va.x; lwa[r][q4+1] = va.y; lwa[r][q4+2] = va.z; lwa[r][q4+3] = va.w;
        float4 vb = *(const float4*)&w_in[r*64 + q4];
        lwb[r][q4] = vb.x; lwb[r][q4+1] = vb.y; lwb[r][q4+2] = vb.z; lwb[r][q4+3] = vb.w;
    }
    __syncthreads();
    int o0 = (tid & 15) * 4;
    int v0 = (tid >> 4) * 4;
    float acc[4][4] = {};
    #pragma unroll 8
    for (int c = 0; c < 64; ++c) {
        float xv[4], wv[4];
        #pragma unroll
        for (int j = 0; j < 4; ++j) { xv[j] = lx[c][v0+j]; wv[j] = lwa[o0+j][c]; }
        #pragma unroll
        for (int vj = 0; vj < 4; ++vj)
            #pragma unroll
            for (int oj = 0; oj < 4; ++oj)
                acc[vj][oj] = fmaf(xv[vj], wv[oj], acc[vj][oj]);
    }
    #pragma unroll
    for (int vj = 0; vj < 4; ++vj) {
        float4 r = make_float4(acc[vj][0], acc[vj][1], acc[vj][2], acc[vj][3]);
        *(float4*)&pre[((size_t)(n*S_ + s0 + v0 + vj))*64 + o0] = r;
    }
    __syncthreads();   // done reading lx as [c][v]
    #pragma unroll
    for (int vj = 0; vj < 4; ++vj)
        #pragma unroll
        for (int oj = 0; oj < 4; ++oj)
            lx[v0+vj][o0+oj] = acc[vj][oj];   // now lx = pre tile [v][c2]
    __syncthreads();
    float acc2[4][4];
    #pragma unroll
    for (int oj = 0; oj < 4; ++oj) {
        float bo = b_in[o0+oj];
        #pragma unroll
        for (int vj = 0; vj < 4; ++vj) acc2[vj][oj] = bo;
    }
    #pragma unroll 8
    for (int c = 0; c < 64; ++c) {
        float fv[4], wv[4];
        #pragma unroll
        for (int j = 0; j < 4; ++j) { fv[j] = lx[v0+j][c]; wv[j] = lwb[c][o0+j]; }
        #pragma unroll
        for (int vj = 0; vj < 4; ++vj)
            #pragma unroll
            for (int oj = 0; oj < 4; ++oj)
                acc2[vj][oj] = fmaf(fv[vj], wv[oj], acc2[vj][oj]);
    }
    #pragma unroll
    for (int vj = 0; vj < 4; ++vj) {
        int vox = s0 + v0 + vj;      // within image n
        int z = vox / HW_;
        int rem = vox - z*HW_;
        int y = rem / W_;
        int xq = rem - y*W_;
        size_t pw = (size_t)n*NSTR_ + (size_t)(z+2)*ZS_ + (y+2)*YS_ + (xq+2)*64 + o0;
        ushort4 pk;
        pk.x = f2bf(acc2[vj][0]); pk.y = f2bf(acc2[vj][1]);
        pk.z = f2bf(acc2[vj][2]); pk.w = f2bf(acc2[vj][3]);
        *(ushort4*)&xprojP[pw] = pk;
    }
}

// depthwise 3x3x3 + instance-norm partials; 4 channels per thread, float4 loads
__global__ __launch_bounds__(256) void k_dw_stats(const float* __restrict__ pre,
        const float* __restrict__ w_dw, float* __restrict__ dw,
        float* __restrict__ psum, float* __restrict__ pss) {
    __shared__ float4 lwd[27][16];     // [tap][c4]
    __shared__ float4 lsum[16][16];    // [xg][c4]
    __shared__ float4 lssum[16][16];
    int b = blockIdx.x;               // n*D*H + z*H + y  (1536)
    int y = b % H_;
    int z = (b / H_) % D_;
    int n = b / (D_*H_);
    int tid = threadIdx.x;
    if (tid < 27*16) {
        int k = tid >> 4, c4 = tid & 15;
        lwd[k][c4] = make_float4(w_dw[(c4*4+0)*27 + k], w_dw[(c4*4+1)*27 + k],
                                 w_dw[(c4*4+2)*27 + k], w_dw[(c4*4+3)*27 + k]);
    }
    __syncthreads();
    int c4 = tid & 15, xg = tid >> 4;
    const float* preN = pre + (size_t)n*S_*64;
    float4 s4 = make_float4(0,0,0,0), ss4 = make_float4(0,0,0,0);
    for (int xx = 0; xx < 6; ++xx) {
        int xi = xg + xx*16;
        float4 acc = make_float4(0,0,0,0);
        #pragma unroll
        for (int dz = 0; dz < 3; ++dz) {
            int zz = z + dz - 1;
            if (zz < 0 || zz >= D_) continue;
            #pragma unroll
            for (int dy = 0; dy < 3; ++dy) {
                int yy = y + dy - 1;
                if (yy < 0 || yy >= H_) continue;
                int rowb = (zz*HW_ + yy*W_)*64 + c4*4;
                #pragma unroll
                for (int dx = 0; dx < 3; ++dx) {
                    int xn = xi + dx - 1;
                    if ((unsigned)xn < (unsigned)W_) {
                        float4 v = *(const float4*)&preN[rowb + (xn<<6)];
                        float4 w = lwd[dz*9+dy*3+dx][c4];
                        acc.x = fmaf(v.x, w.x, acc.x);
                        acc.y = fmaf(v.y, w.y, acc.y);
                        acc.z = fmaf(v.z, w.z, acc.z);
                        acc.w = fmaf(v.w, w.w, acc.w);
                    }
                }
            }
        }
        *(float4*)&dw[((size_t)n*S_ + z*HW_ + y*W_ + xi)*64 + c4*4] = acc;
        s4.x += acc.x; s4.y += acc.y; s4.z += acc.z; s4.w += acc.w;
        ss4.x = fmaf(acc.x, acc.x, ss4.x); ss4.y = fmaf(acc.y, acc.y, ss4.y);
        ss4.z = fmaf(acc.z, acc.z, ss4.z); ss4.w = fmaf(acc.w, acc.w, ss4.w);
    }
    lsum[xg][c4] = s4; lssum[xg][c4] = ss4;
    __syncthreads();
    if (tid < 64) {
        float s = 0.f, ss = 0.f;
        #pragma unroll
        for (int k = 0; k < 16; ++k) {
            s  += ((const float*)&lsum [k][tid>>2])[tid&3];
            ss += ((const float*)&lssum[k][tid>>2])[tid&3];
        }
        psum[tid*1536 + b] = s;
        pss [tid*1536 + b] = ss;
    }
}

// reduce partials -> mean / rsqrt(var)
__global__ void k_stats2(const float* __restrict__ psum, const float* __restrict__ pss,
                         float* __restrict__ stats) {
    int u = blockIdx.x;               // 0..127
    int n = u >> 6, c = u & 63;
    int l = threadIdx.x;              // 0..63
    float s = 0.f, ss = 0.f;
    #pragma unroll
    for (int k = 0; k < 12; ++k) {
        int row = n*768 + k*64 + l;
        s  += psum[c*1536 + row];
        ss += pss [c*1536 + row];
    }
    #pragma unroll
    for (int o2 = 32; o2 >= 1; o2 >>= 1) {
        s  += __shfl_xor(s, o2);
        ss += __shfl_xor(ss, o2);
    }
    if (l == 0) {
        float inv = 1.f / (float)S_;
        float mean = s * inv;
        float var = ss * inv - mean*mean;
        stats[n*128 + c] = mean;
        stats[n*128 + 64 + c] = rsqrtf(var + 1e-5f);
    }
}

// fused DCN: block = 1z x 4y x 8x = 32 voxels (64 pairs); descriptor precompute + bf16 gather
__global__ __launch_bounds__(256) void k_dcn(const unsigned short* __restrict__ xprojP,
        const float* __restrict__ dw, const float* __restrict__ stats,
        const float4* __restrict__ woffT4, const float4* __restrict__ b4f,
        unsigned short* __restrict__ coreB) {
    __shared__ union {
        float featT[64][36];            // [c][vox] (phases 1a/1b)
        int   cwl[64][27];              // [pair][tap] base word offset (phases 2a/2b)
    } uS;
    __shared__ float4 offs4[64][29];    // [pair][tap]: dx,dy,dz,logit->prob ; then desc uint4
    int tid = threadIdx.x;
    // bijective XCD swizzle: 4608 blocks = 8 * 576
    int orig = blockIdx.x;
    int bid = (orig & 7) * 576 + (orig >> 3);
    int x8 = bid % 12;
    int t1 = bid / 12;
    int y4 = t1 % 24;
    int t2 = t1 / 24;                 // 0..15
    int z  = t2 & 7;
    int n  = t2 >> 3;
    int yb = y4*4, xb = x8*8;
    size_t voxBase = (size_t)n*S_ + (size_t)z*HW_ + yb*W_ + xb;

    // 1a: feat = gelu(instnorm(dw)) transposed into LDS (2 voxels x 4ch per thread)
    {
        int c4 = (tid & 15) * 4;
        int vp = tid >> 4;
        #pragma unroll
        for (int j = 0; j < 2; ++j) {
            int vloc = vp*2 + j;
            size_t vox = voxBase + (vloc>>3)*W_ + (vloc & 7);
            float4 v = *(const float4*)&dw[vox*64 + c4];
            float vals[4] = {v.x, v.y, v.z, v.w};
            #pragma unroll
            for (int jj = 0; jj < 4; ++jj) {
                int c = c4 + jj;
                float t = (vals[jj] - stats[n*128+c]) * stats[n*128+64+c];
                uS.featT[c][vloc] = gelu_fast(t);
            }
        }
    }
    __syncthreads();

    // 1b: offset/mask projection; thread = (u=(g,p), 8-voxel octet)
    if (tid < 216) {
        int q = tid / 54;             // 0..3 -> voxels q*8..q*8+7
        int u = tid - q*54;
        int g = u / 27, p = u - g*27;
        float4 bb = b4f[u];
        float4 aa[8];
        #pragma unroll
        for (int j = 0; j < 8; ++j) aa[j] = bb;
        for (int c = 0; c < 64; ++c) {
            float4 w = woffT4[c*64 + u];
            float4 f0 = *(const float4*)&uS.featT[c][q*8];
            float4 f1 = *(const float4*)&uS.featT[c][q*8 + 4];
            float ff[8] = {f0.x, f0.y, f0.z, f0.w, f1.x, f1.y, f1.z, f1.w};
            #pragma unroll
            for (int j = 0; j < 8; ++j) {
                aa[j].x = fmaf(ff[j], w.x, aa[j].x);
                aa[j].y = fmaf(ff[j], w.y, aa[j].y);
                aa[j].z = fmaf(ff[j], w.z, aa[j].z);
                aa[j].w = fmaf(ff[j], w.w, aa[j].w);
            }
        }
        #pragma unroll
        for (int j = 0; j < 8; ++j)
            offs4[(q*8+j)*2 + g][p] = aa[j];
    }
    __syncthreads();

    // softmax over taps per pair (64 pairs)
    if (tid < 64) {
        float mx = -1e30f;
        #pragma unroll
        for (int p = 0; p < 27; ++p) mx = fmaxf(mx, offs4[tid][p].w);
        float e[27]; float ssum = 0.f;
        #pragma unroll
        for (int p = 0; p < 27; ++p) { e[p] = __expf(offs4[tid][p].w - mx); ssum += e[p]; }
        float inv = __builtin_amdgcn_rcpf(ssum);
        #pragma unroll
        for (int p = 0; p < 27; ++p) offs4[tid][p].w = e[p]*inv;
    }
    __syncthreads();

    // 2a: tap descriptors — 8 trilinear corner weights (bf16-packed) + base offset,
    // computed once per (pair,tap), stored in place over offs4 (+ cwl over dead featT)
    {
        int zm1 = z - 1;
        #pragma unroll
        for (int k = 0; k < 7; ++k) {
            int idx = tid + k*256;
            if (idx < 1728) {
                int pair = idx / 27;
                int p = idx - pair*27;
                float4 tp = offs4[pair][p];
                int vloc = pair >> 1, g = pair & 1;
                int yy = vloc >> 3, xx = vloc & 7;
                float zf = (float)(zm1 + p/9) + tp.z;
                float yf = (float)(yb + yy - 1 + (p/3)%3) + tp.y;
                float xf = (float)(xb + xx - 1 + p%3) + tp.x;
                zf = fminf(fmaxf(zf, -1.5f), (float)D_ + 0.5f);
                yf = fminf(fmaxf(yf, -1.5f), (float)H_ + 0.5f);
                xf = fminf(fmaxf(xf, -1.5f), (float)W_ + 0.5f);
                float z0f = floorf(zf), y0f = floorf(yf), x0f = floorf(xf);
                float fz = zf - z0f, fy = yf - y0f, fx = xf - x0f;
                int zi = (int)z0f, yi = (int)y0f, xi = (int)x0f;
                float wz1 = fz * tp.w, wz0 = tp.w - wz1;   // prob folded in
                float wy1 = fy, wy0 = 1.f - fy;
                float wx1 = fx, wx0 = 1.f - fx;
                float w00 = wz0*wy0, w01 = wz0*wy1, w10 = wz1*wy0, w11 = wz1*wy1;
                unsigned u0 = pkhi(w00*wx1, w00*wx0);   // {c001, c000}
                unsigned u1 = pkhi(w01*wx1, w01*wx0);   // {c011, c010}
                unsigned u2 = pkhi(w10*wx1, w10*wx0);   // {c101, c100}
                unsigned u3 = pkhi(w11*wx1, w11*wx0);   // {c111, c110}
                int cw = zi*ZS_ + yi*YS_ + (xi<<6) + (2*ZS_ + 2*YS_ + 128) + g*32;
                *(uint4*)&offs4[pair][p] = make_uint4(u0,u1,u2,u3);
                uS.cwl[pair][p] = cw;
            }
        }
    }
    __syncthreads();

    // 2b: gather — 4 lanes x 8 bf16 channels per (voxel,g); zero pad ring -> no bounds tests
    int pair = tid >> 2;              // 0..63
    int vloc = pair >> 1, g = pair & 1;
    int yy = vloc >> 3, xx = vloc & 7;
    int ch4 = (tid & 3) * 8;          // channel offset within group
    const unsigned short* __restrict__ base = xprojP + (size_t)n*NSTR_ + ch4;
    float a0=0.f,a1=0.f,a2=0.f,a3=0.f,a4=0.f,a5=0.f,a6=0.f,a7=0.f;
    #pragma unroll
    for (int p = 0; p < 27; ++p) {
        uint4 dsc = *(const uint4*)&offs4[pair][p];
        int cw = uS.cwl[pair][p];
        const unsigned short* p00 = base + cw;
        const unsigned short* p01 = p00 + YS_;
        const unsigned short* p10 = p00 + ZS_;
        const unsigned short* p11 = p10 + YS_;
        uint4 q000 = *(const uint4*)p00;
        uint4 q001 = *(const uint4*)(p00 + 64);
        uint4 q010 = *(const uint4*)p01;
        uint4 q011 = *(const uint4*)(p01 + 64);
        uint4 q100 = *(const uint4*)p10;
        uint4 q101 = *(const uint4*)(p10 + 64);
        uint4 q110 = *(const uint4*)p11;
        uint4 q111 = *(const uint4*)(p11 + 64);
        float c000 = __uint_as_float(dsc.x << 16), c001 = __uint_as_float(dsc.x);
        float c010 = __uint_as_float(dsc.y << 16), c011 = __uint_as_float(dsc.y);
        float c100 = __uint_as_float(dsc.z << 16), c101 = __uint_as_float(dsc.z);
        float c110 = __uint_as_float(dsc.w << 16), c111 = __uint_as_float(dsc.w);
        // hi channel uses raw word (garbage low mantissa ~2^-8 rel: harmless)
        #define ACC8(Q, WGT) { \
            float wq = (WGT); \
            a0 = fmaf(wq, __uint_as_float((Q).x << 16), a0); \
            a1 = fmaf(wq, __uint_as_float((Q).x), a1); \
            a2 = fmaf(wq, __uint_as_float((Q).y << 16), a2); \
            a3 = fmaf(wq, __uint_as_float((Q).y), a3); \
            a4 = fmaf(wq, __uint_as_float((Q).z << 16), a4); \
            a5 = fmaf(wq, __uint_as_float((Q).z), a5); \
            a6 = fmaf(wq, __uint_as_float((Q).w << 16), a6); \
            a7 = fmaf(wq, __uint_as_float((Q).w), a7); \
        }
        ACC8(q000, c000); ACC8(q001, c001); ACC8(q010, c010); ACC8(q011, c011);
        ACC8(q100, c100); ACC8(q101, c101); ACC8(q110, c110); ACC8(q111, c111);
        #undef ACC8
    }
    size_t voxOut = voxBase + yy*W_ + xx;
    unsigned r01 = pkhi(a1, a0);
    unsigned r23 = pkhi(a3, a2);
    unsigned r45 = pkhi(a5, a4);
    unsigned r67 = pkhi(a7, a6);
    *(uint4*)&coreB[voxOut*64 + g*32 + ch4] = make_uint4(r01, r23, r45, r67);
}

// out = x + sigmoid(gate) * (core @ W2 + B2), back to NCDHW  (core in bf16)
__global__ __launch_bounds__(256) void k_final(const unsigned short* __restrict__ coreB,
        const float* __restrict__ W2, const float* __restrict__ B2,
        const float* __restrict__ x, const float* __restrict__ gate,
        float* __restrict__ out) {
    __shared__ float lc[64][65];   // [v][c]
    __shared__ float lw[64][65];   // [c][o]
    int b = blockIdx.x;
    int n = b / 1152;
    int s0 = (b % 1152) * 64;
    int tid = threadIdx.x;
    for (int idx = tid; idx < 512; idx += 256) {
        int r = idx >> 3, q8 = (idx & 7) * 8;
        uint4 q = *(const uint4*)&coreB[((size_t)(n*S_ + s0 + r))*64 + q8];
        lc[r][q8+0] = __uint_as_float(q.x << 16);
        lc[r][q8+1] = __uint_as_float(q.x & 0xffff0000u);
        lc[r][q8+2] = __uint_as_float(q.y << 16);
        lc[r][q8+3] = __uint_as_float(q.y & 0xffff0000u);
        lc[r][q8+4] = __uint_as_float(q.z << 16);
        lc[r][q8+5] = __uint_as_float(q.z & 0xffff0000u);
        lc[r][q8+6] = __uint_as_float(q.w << 16);
        lc[r][q8+7] = __uint_as_float(q.w & 0xffff0000u);
    }
    for (int idx = tid; idx < 1024; idx += 256) {
        int r = idx >> 4, q4 = (idx & 15) * 4;
        float4 vw = *(const float4*)&W2[r*64 + q4];
        lw[r][q4] = vw.x; lw[r][q4+1] = vw.y; lw[r][q4+2] = vw.z; lw[r][q4+3] = vw.w;
    }
    __syncthreads();
    float sg = 1.f / (1.f + expf(-gate[0]));
    int o0 = (tid & 15) * 4;
    int v0 = (tid >> 4) * 4;
    float acc[4][4];
    #pragma unroll
    for (int oj = 0; oj < 4; ++oj) {
        float bo = B2[o0+oj];
        #pragma unroll
        for (int vj = 0; vj < 4; ++vj) acc[vj][oj] = bo;
    }
    #pragma unroll 8
    for (int c = 0; c < 64; ++c) {
        float fv[4], wv[4];
        #pragma unroll
        for (int j = 0; j < 4; ++j) { fv[j] = lc[v0+j][c]; wv[j] = lw[c][o0+j]; }
        #pragma unroll
        for (int vj = 0; vj < 4; ++vj)
            #pragma unroll
            for (int oj = 0; oj < 4; ++oj)
                acc[vj][oj] = fmaf(fv[vj], wv[oj], acc[vj][oj]);
    }
    #pragma unroll
    for (int oj = 0; oj < 4; ++oj) {
        size_t gi = ((size_t)(n*64 + o0 + oj))*S_ + s0 + v0;
        float4 xv = *(const float4*)&x[gi];
        float4 r;
        r.x = fmaf(sg, acc[0][oj], xv.x);
        r.y = fmaf(sg, acc[1][oj], xv.y);
        r.z = fmaf(sg, acc[2][oj], xv.z);
        r.w = fmaf(sg, acc[3][oj], xv.w);
        *(float4*)&out[gi] = r;
    }
}

extern "C" void kernel_launch(void* const* d_in, const int* in_sizes, int n_in,
                              void* d_out, int out_size, void* d_ws, size_t ws_size,
                              hipStream_t stream) {
    const float* x      = (const float*)d_in[0];
    const float* w_pre  = (const float*)d_in[1];
    const float* w_in   = (const float*)d_in[2];
    const float* b_in   = (const float*)d_in[3];
    const float* w_dw   = (const float*)d_in[4];
    const float* w_off  = (const float*)d_in[5];
    const float* b_off  = (const float*)d_in[6];
    const float* w_mask = (const float*)d_in[7];
    const float* b_mask = (const float*)d_in[8];
    const float* w_out  = (const float*)d_in[9];
    const float* b_out  = (const float*)d_in[10];
    const float* w_post = (const float*)d_in[11];
    const float* gate   = (const float*)d_in[12];
    float* out = (float*)d_out;

    float* ws      = (float*)d_ws;
    unsigned short* xprojP = (unsigned short*)ws;      // 15,360,000 ushorts
    float* pre     = ws + (size_t)7680000;             // 9,437,184 floats
    unsigned short* coreB = (unsigned short*)(pre + (size_t)9437184);  // 9,437,184 ushorts
    float* psum    = (float*)(coreB + (size_t)9437184);// 98,304
    float* pss     = psum + 98304;                     // 98,304
    float* stats   = pss + 98304;                      // 256
    float* W2      = stats + 256;                      // 4,096
    float* B2      = W2 + 4096;                        // 64 (+pad)
    float4* woffT4 = (float4*)(B2 + 128);              // 64*64 float4
    float4* b4f    = woffT4 + 4096;                    // 54 float4 (+pad)
    float* dwb     = out;                              // d_out doubles as dw scratch

    hipMemsetAsync(xprojP, 0, (size_t)15360000*sizeof(unsigned short), stream);
    hipLaunchKernelGGL(k_prep,     dim3(64),   dim3(64),  0, stream,
                       w_out, b_out, w_post, w_off, b_off, w_mask, b_mask,
                       W2, B2, woffT4, b4f);
    hipLaunchKernelGGL(k_pre_proj, dim3(2304), dim3(256), 0, stream,
                       x, w_pre, w_in, b_in, pre, xprojP);
    hipLaunchKernelGGL(k_dw_stats, dim3(1536), dim3(256), 0, stream,
                       pre, w_dw, dwb, psum, pss);
    hipLaunchKernelGGL(k_stats2,   dim3(128),  dim3(64),  0, stream, psum, pss, stats);
    hipLaunchKernelGGL(k_dcn,      dim3(4608), dim3(256), 0, stream,
                       xprojP, dwb, stats, woffT4, b4f, coreB);
    hipLaunchKernelGGL(k_final,    dim3(2304), dim3(256), 0, stream,
                       coreB, W2, B2, x, gate, out);
}

// Round 7
// 324.527 us; speedup vs baseline: 3.1433x; 1.0149x over previous
//
#include <hip/hip_runtime.h>
#include <math.h>

#define N_ 2
#define C_ 64
#define D_ 8
#define H_ 96
#define W_ 96
#define S_ (D_*H_*W_)   // 73728
#define HW_ (H_*W_)     // 9216
// padded xproj (bf16): [n][z+2 of 12][y+2 of 100][x+2 of 100][64]
#define ZP_ 12
#define YP_ 100
#define XP_ 100
#define NSTR_ (ZP_*YP_*XP_*64)   // 7680000 elements
#define ZS_ (YP_*XP_*64)         // 640000
#define YS_ (XP_*64)             // 6400

typedef __attribute__((ext_vector_type(8))) short short8;
typedef __attribute__((ext_vector_type(4))) float f32x4;

__device__ __forceinline__ float gelu_fast(float x) {
    float a = 0.7978845608028654f * (x + 0.044715f*x*x*x);
    float E = __expf(2.f*a);
    return x - x * __builtin_amdgcn_rcpf(E + 1.f);
}

__device__ __forceinline__ unsigned short f2bf(float f) {   // RNE bf16
    unsigned u = __float_as_uint(f);
    unsigned r = (u + 0x7fffu + ((u >> 16) & 1u)) >> 16;
    return (unsigned short)r;
}

// pack top-16 of two f32 into one uint: {hi16(a), hi16(b)}
__device__ __forceinline__ unsigned pkhi(float a, float b) {
    return __builtin_amdgcn_perm(__float_as_uint(a), __float_as_uint(b), 0x07060302u);
}

// prep: W2 = w_out @ w_post^T folded, B2; wBg[m=u*4+comp][c] bf16 proj weights
// (AXIS_SCALE folded, rows 216..223 zero); b4f[u] = bias float4
__global__ __launch_bounds__(64) void k_prep(const float* __restrict__ w_out,
        const float* __restrict__ b_out, const float* __restrict__ w_post,
        const float* __restrict__ w_off, const float* __restrict__ b_off,
        const float* __restrict__ w_mask, const float* __restrict__ b_mask,
        float* __restrict__ W2, float* __restrict__ B2,
        unsigned short* __restrict__ wBg, float4* __restrict__ b4f) {
    int b = blockIdx.x;      // 0..63
    int t = threadIdx.x;     // 0..63
    float acc = 0.f;
    for (int c = 0; c < 64; ++c)
        acc = fmaf(w_out[b*64+c], w_post[t*64+c], acc);
    W2[b*64 + t] = acc;
    if (b == 0) {
        float a2 = 0.f;
        for (int c = 0; c < 64; ++c)
            a2 = fmaf(w_post[t*64+c], b_out[c], a2);
        B2[t] = a2;
    }
    {
        int c = b;
        for (int m = t; m < 224; m += 64) {
            float v = 0.f;
            if (m < 216) {
                int u = m >> 2, comp = m & 3;
                if (comp == 3) v = w_mask[c*54 + u];
                else {
                    v = w_off[c*162 + u*3 + comp];
                    if (comp == 0) v *= 0.5f;
                }
            }
            wBg[m*64 + c] = f2bf(v);
        }
    }
    if (b == 1 && t < 54)
        b4f[t] = make_float4(b_off[t*3]*0.5f, b_off[t*3+1], b_off[t*3+2], b_mask[t]);
}

// fused: pre = x @ w_pre^T (fp32, for dw), xprojP = bf16(pre @ w_in + b_in) padded
__global__ __launch_bounds__(256) void k_pre_proj(const float* __restrict__ x,
        const float* __restrict__ w_pre, const float* __restrict__ w_in,
        const float* __restrict__ b_in, float* __restrict__ pre,
        unsigned short* __restrict__ xprojP) {
    __shared__ float lx[64][65];    // [c][v] then reused as [v][c2]
    __shared__ float lwa[64][65];   // w_pre [o][c]
    __shared__ float lwb[64][65];   // w_in  [c][o]
    int b = blockIdx.x;
    int n = b / 1152;
    int s0 = (b % 1152) * 64;
    int tid = threadIdx.x;
    for (int idx = tid; idx < 1024; idx += 256) {
        int r = idx >> 4, q4 = (idx & 15) * 4;
        float4 vx = *(const float4*)&x[((size_t)(n*C_ + r))*S_ + s0 + q4];
        lx[r][q4] = vx.x; lx[r][q4+1] = vx.y; lx[r][q4+2] = vx.z; lx[r][q4+3] = vx.w;
        float4 va = *(const float4*)&w_pre[r*64 + q4];
        lwa[r][q4] = va.x; lwa[r][q4+1] = va.y; lwa[r][q4+2] = va.z; lwa[r][q4+3] = va.w;
        float4 vb = *(const float4*)&w_in[r*64 + q4];
        lwb[r][q4] = vb.x; lwb[r][q4+1] = vb.y; lwb[r][q4+2] = vb.z; lwb[r][q4+3] = vb.w;
    }
    __syncthreads();
    int o0 = (tid & 15) * 4;
    int v0 = (tid >> 4) * 4;
    float acc[4][4] = {};
    #pragma unroll 8
    for (int c = 0; c < 64; ++c) {
        float xv[4], wv[4];
        #pragma unroll
        for (int j = 0; j < 4; ++j) { xv[j] = lx[c][v0+j]; wv[j] = lwa[o0+j][c]; }
        #pragma unroll
        for (int vj = 0; vj < 4; ++vj)
            #pragma unroll
            for (int oj = 0; oj < 4; ++oj)
                acc[vj][oj] = fmaf(xv[vj], wv[oj], acc[vj][oj]);
    }
    #pragma unroll
    for (int vj = 0; vj < 4; ++vj) {
        float4 r = make_float4(acc[vj][0], acc[vj][1], acc[vj][2], acc[vj][3]);
        *(float4*)&pre[((size_t)(n*S_ + s0 + v0 + vj))*64 + o0] = r;
    }
    __syncthreads();   // done reading lx as [c][v]
    #pragma unroll
    for (int vj = 0; vj < 4; ++vj)
        #pragma unroll
        for (int oj = 0; oj < 4; ++oj)
            lx[v0+vj][o0+oj] = acc[vj][oj];   // now lx = pre tile [v][c2]
    __syncthreads();
    float acc2[4][4];
    #pragma unroll
    for (int oj = 0; oj < 4; ++oj) {
        float bo = b_in[o0+oj];
        #pragma unroll
        for (int vj = 0; vj < 4; ++vj) acc2[vj][oj] = bo;
    }
    #pragma unroll 8
    for (int c = 0; c < 64; ++c) {
        float fv[4], wv[4];
        #pragma unroll
        for (int j = 0; j < 4; ++j) { fv[j] = lx[v0+j][c]; wv[j] = lwb[c][o0+j]; }
        #pragma unroll
        for (int vj = 0; vj < 4; ++vj)
            #pragma unroll
            for (int oj = 0; oj < 4; ++oj)
                acc2[vj][oj] = fmaf(fv[vj], wv[oj], acc2[vj][oj]);
    }
    #pragma unroll
    for (int vj = 0; vj < 4; ++vj) {
        int vox = s0 + v0 + vj;      // within image n
        int z = vox / HW_;
        int rem = vox - z*HW_;
        int y = rem / W_;
        int xq = rem - y*W_;
        size_t pw = (size_t)n*NSTR_ + (size_t)(z+2)*ZS_ + (y+2)*YS_ + (xq+2)*64 + o0;
        ushort4 pk;
        pk.x = f2bf(acc2[vj][0]); pk.y = f2bf(acc2[vj][1]);
        pk.z = f2bf(acc2[vj][2]); pk.w = f2bf(acc2[vj][3]);
        *(ushort4*)&xprojP[pw] = pk;
    }
}

// depthwise 3x3x3 + instance-norm partials; 4 channels per thread, float4 loads
__global__ __launch_bounds__(256) void k_dw_stats(const float* __restrict__ pre,
        const float* __restrict__ w_dw, float* __restrict__ dw,
        float* __restrict__ psum, float* __restrict__ pss) {
    __shared__ float4 lwd[27][16];     // [tap][c4]
    __shared__ float4 lsum[16][16];    // [xg][c4]
    __shared__ float4 lssum[16][16];
    int b = blockIdx.x;               // n*D*H + z*H + y  (1536)
    int y = b % H_;
    int z = (b / H_) % D_;
    int n = b / (D_*H_);
    int tid = threadIdx.x;
    if (tid < 27*16) {
        int k = tid >> 4, c4 = tid & 15;
        lwd[k][c4] = make_float4(w_dw[(c4*4+0)*27 + k], w_dw[(c4*4+1)*27 + k],
                                 w_dw[(c4*4+2)*27 + k], w_dw[(c4*4+3)*27 + k]);
    }
    __syncthreads();
    int c4 = tid & 15, xg = tid >> 4;
    const float* preN = pre + (size_t)n*S_*64;
    float4 s4 = make_float4(0,0,0,0), ss4 = make_float4(0,0,0,0);
    for (int xx = 0; xx < 6; ++xx) {
        int xi = xg + xx*16;
        float4 acc = make_float4(0,0,0,0);
        #pragma unroll
        for (int dz = 0; dz < 3; ++dz) {
            int zz = z + dz - 1;
            if (zz < 0 || zz >= D_) continue;
            #pragma unroll
            for (int dy = 0; dy < 3; ++dy) {
                int yy = y + dy - 1;
                if (yy < 0 || yy >= H_) continue;
                int rowb = (zz*HW_ + yy*W_)*64 + c4*4;
                #pragma unroll
                for (int dx = 0; dx < 3; ++dx) {
                    int xn = xi + dx - 1;
                    if ((unsigned)xn < (unsigned)W_) {
                        float4 v = *(const float4*)&preN[rowb + (xn<<6)];
                        float4 w = lwd[dz*9+dy*3+dx][c4];
                        acc.x = fmaf(v.x, w.x, acc.x);
                        acc.y = fmaf(v.y, w.y, acc.y);
                        acc.z = fmaf(v.z, w.z, acc.z);
                        acc.w = fmaf(v.w, w.w, acc.w);
                    }
                }
            }
        }
        *(float4*)&dw[((size_t)n*S_ + z*HW_ + y*W_ + xi)*64 + c4*4] = acc;
        s4.x += acc.x; s4.y += acc.y; s4.z += acc.z; s4.w += acc.w;
        ss4.x = fmaf(acc.x, acc.x, ss4.x); ss4.y = fmaf(acc.y, acc.y, ss4.y);
        ss4.z = fmaf(acc.z, acc.z, ss4.z); ss4.w = fmaf(acc.w, acc.w, ss4.w);
    }
    lsum[xg][c4] = s4; lssum[xg][c4] = ss4;
    __syncthreads();
    if (tid < 64) {
        float s = 0.f, ss = 0.f;
        #pragma unroll
        for (int k = 0; k < 16; ++k) {
            s  += ((const float*)&lsum [k][tid>>2])[tid&3];
            ss += ((const float*)&lssum[k][tid>>2])[tid&3];
        }
        psum[tid*1536 + b] = s;
        pss [tid*1536 + b] = ss;
    }
}

// reduce partials -> mean / rsqrt(var)
__global__ void k_stats2(const float* __restrict__ psum, const float* __restrict__ pss,
                         float* __restrict__ stats) {
    int u = blockIdx.x;               // 0..127
    int n = u >> 6, c = u & 63;
    int l = threadIdx.x;              // 0..63
    float s = 0.f, ss = 0.f;
    #pragma unroll
    for (int k = 0; k < 12; ++k) {
        int row = n*768 + k*64 + l;
        s  += psum[c*1536 + row];
        ss += pss [c*1536 + row];
    }
    #pragma unroll
    for (int o2 = 32; o2 >= 1; o2 >>= 1) {
        s  += __shfl_xor(s, o2);
        ss += __shfl_xor(ss, o2);
    }
    if (l == 0) {
        float inv = 1.f / (float)S_;
        float mean = s * inv;
        float var = ss * inv - mean*mean;
        stats[n*128 + c] = mean;
        stats[n*128 + 64 + c] = rsqrtf(var + 1e-5f);
    }
}

// fused DCN: block = 1z x 4y x 8x = 32 voxels (64 pairs)
// 1b projection done via MFMA: D[224][32] = wBg[224x64] @ featB[64x32]
__global__ __launch_bounds__(256) void k_dcn(const unsigned short* __restrict__ xprojP,
        const float* __restrict__ dw, const float* __restrict__ stats,
        const unsigned short* __restrict__ wBg, const float4* __restrict__ b4f,
        unsigned short* __restrict__ coreB) {
    __shared__ union {
        unsigned short featB[32][64];   // [vox][k] bf16, 16B-block swizzled by vox&7
        int cwl[64][27];                // [pair][tap] base word offset (2a/2b)
    } uS;
    __shared__ float4 offs4[64][29];    // [pair][tap]: dx,dy,dz,logit->prob ; then desc uint4
    int tid = threadIdx.x;
    // bijective XCD swizzle: 4608 blocks = 8 * 576
    int orig = blockIdx.x;
    int bid = (orig & 7) * 576 + (orig >> 3);
    int x8 = bid % 12;
    int t1 = bid / 12;
    int y4 = t1 % 24;
    int t2 = t1 / 24;                 // 0..15
    int z  = t2 & 7;
    int n  = t2 >> 3;
    int yb = y4*4, xb = x8*8;
    size_t voxBase = (size_t)n*S_ + (size_t)z*HW_ + yb*W_ + xb;

    // 1a: feat = gelu(instnorm(dw)) -> bf16 into featB[vox][k] (swizzled 16B blocks)
    {
        int c4 = (tid & 15) * 4;
        int vp = tid >> 4;
        #pragma unroll
        for (int j = 0; j < 2; ++j) {
            int vloc = vp*2 + j;
            size_t vox = voxBase + (vloc>>3)*W_ + (vloc & 7);
            float4 v = *(const float4*)&dw[vox*64 + c4];
            float vals[4] = {v.x, v.y, v.z, v.w};
            ushort4 pk;
            unsigned short* pp = (unsigned short*)&pk;
            #pragma unroll
            for (int jj = 0; jj < 4; ++jj) {
                int c = c4 + jj;
                float t = (vals[jj] - stats[n*128+c]) * stats[n*128+64+c];
                pp[jj] = f2bf(gelu_fast(t));
            }
            int off = ((((c4 >> 3) ^ (vloc & 7)) << 3) | (c4 & 7));
            *(ushort4*)&uS.featB[vloc][off] = pk;
        }
    }
    __syncthreads();

    // 1b: MFMA projection. 28 (m,n) tiles of 16x16, 4 waves x 7 tiles, K=64 (2 halves).
    {
        int w = tid >> 6;
        int l = tid & 63;
        int lr = l & 15;          // 16-dim index (m for A, n/vox for B/D col)
        int lq = l >> 4;          // 0..3
        for (int i = 0; i < 7; ++i) {
            int t7 = w*7 + i;
            int mt = t7 >> 1, nt = t7 & 1;
            int vox = nt*16 + lr;
            f32x4 acc = {0.f, 0.f, 0.f, 0.f};
            #pragma unroll
            for (int h = 0; h < 2; ++h) {
                int k0 = h*32 + lq*8;
                short8 af = *(const short8*)&wBg[(mt*16 + lr)*64 + k0];
                int blk = (((k0 >> 3) ^ (vox & 7)) << 3);
                short8 bf = *(const short8*)&uS.featB[vox][blk];
                acc = __builtin_amdgcn_mfma_f32_16x16x32_bf16(af, bf, acc, 0, 0, 0);
            }
            int u = mt*4 + lq;            // output u54; comps = regs
            if (u < 54) {
                float4 bb = b4f[u];
                int g = (u >= 27) ? 1 : 0;
                int p = u - g*27;
                offs4[vox*2 + g][p] = make_float4(acc[0] + bb.x, acc[1] + bb.y,
                                                  acc[2] + bb.z, acc[3] + bb.w);
            }
        }
    }
    __syncthreads();

    // softmax over taps per pair (64 pairs)
    if (tid < 64) {
        float mx = -1e30f;
        #pragma unroll
        for (int p = 0; p < 27; ++p) mx = fmaxf(mx, offs4[tid][p].w);
        float e[27]; float ssum = 0.f;
        #pragma unroll
        for (int p = 0; p < 27; ++p) { e[p] = __expf(offs4[tid][p].w - mx); ssum += e[p]; }
        float inv = __builtin_amdgcn_rcpf(ssum);
        #pragma unroll
        for (int p = 0; p < 27; ++p) offs4[tid][p].w = e[p]*inv;
    }
    __syncthreads();

    // 2a: tap descriptors — 8 corner weights (bf16-packed) + base offset, once per (pair,tap)
    {
        int zm1 = z - 1;
        #pragma unroll
        for (int k = 0; k < 7; ++k) {
            int idx = tid + k*256;
            if (idx < 1728) {
                int pair = idx / 27;
                int p = idx - pair*27;
                float4 tp = offs4[pair][p];
                int vloc = pair >> 1, g = pair & 1;
                int yy = vloc >> 3, xx = vloc & 7;
                float zf = (float)(zm1 + p/9) + tp.z;
                float yf = (float)(yb + yy - 1 + (p/3)%3) + tp.y;
                float xf = (float)(xb + xx - 1 + p%3) + tp.x;
                zf = fminf(fmaxf(zf, -1.5f), (float)D_ + 0.5f);
                yf = fminf(fmaxf(yf, -1.5f), (float)H_ + 0.5f);
                xf = fminf(fmaxf(xf, -1.5f), (float)W_ + 0.5f);
                float z0f = floorf(zf), y0f = floorf(yf), x0f = floorf(xf);
                float fz = zf - z0f, fy = yf - y0f, fx = xf - x0f;
                int zi = (int)z0f, yi = (int)y0f, xi = (int)x0f;
                float wz1 = fz * tp.w, wz0 = tp.w - wz1;   // prob folded in
                float wy1 = fy, wy0 = 1.f - fy;
                float wx1 = fx, wx0 = 1.f - fx;
                float w00 = wz0*wy0, w01 = wz0*wy1, w10 = wz1*wy0, w11 = wz1*wy1;
                unsigned u0 = pkhi(w00*wx1, w00*wx0);   // {c001, c000}
                unsigned u1 = pkhi(w01*wx1, w01*wx0);   // {c011, c010}
                unsigned u2 = pkhi(w10*wx1, w10*wx0);   // {c101, c100}
                unsigned u3 = pkhi(w11*wx1, w11*wx0);   // {c111, c110}
                int cw = zi*ZS_ + yi*YS_ + (xi<<6) + (2*ZS_ + 2*YS_ + 128) + g*32;
                *(uint4*)&offs4[pair][p] = make_uint4(u0,u1,u2,u3);
                uS.cwl[pair][p] = cw;
            }
        }
    }
    __syncthreads();

    // 2b: gather — 4 lanes x 8 bf16 channels per (voxel,g); zero pad ring -> no bounds tests
    int pair = tid >> 2;              // 0..63
    int vloc = pair >> 1, g = pair & 1;
    int yy = vloc >> 3, xx = vloc & 7;
    int ch4 = (tid & 3) * 8;          // channel offset within group
    const unsigned short* __restrict__ base = xprojP + (size_t)n*NSTR_ + ch4;
    float a0=0.f,a1=0.f,a2=0.f,a3=0.f,a4=0.f,a5=0.f,a6=0.f,a7=0.f;
    #pragma unroll
    for (int p = 0; p < 27; ++p) {
        uint4 dsc = *(const uint4*)&offs4[pair][p];
        int cw = uS.cwl[pair][p];
        const unsigned short* p00 = base + cw;
        const unsigned short* p01 = p00 + YS_;
        const unsigned short* p10 = p00 + ZS_;
        const unsigned short* p11 = p10 + YS_;
        uint4 q000 = *(const uint4*)p00;
        uint4 q001 = *(const uint4*)(p00 + 64);
        uint4 q010 = *(const uint4*)p01;
        uint4 q011 = *(const uint4*)(p01 + 64);
        uint4 q100 = *(const uint4*)p10;
        uint4 q101 = *(const uint4*)(p10 + 64);
        uint4 q110 = *(const uint4*)p11;
        uint4 q111 = *(const uint4*)(p11 + 64);
        float c000 = __uint_as_float(dsc.x << 16), c001 = __uint_as_float(dsc.x);
        float c010 = __uint_as_float(dsc.y << 16), c011 = __uint_as_float(dsc.y);
        float c100 = __uint_as_float(dsc.z << 16), c101 = __uint_as_float(dsc.z);
        float c110 = __uint_as_float(dsc.w << 16), c111 = __uint_as_float(dsc.w);
        // hi channel uses raw word (garbage low mantissa ~2^-8 rel: harmless)
        #define ACC8(Q, WGT) { \
            float wq = (WGT); \
            a0 = fmaf(wq, __uint_as_float((Q).x << 16), a0); \
            a1 = fmaf(wq, __uint_as_float((Q).x), a1); \
            a2 = fmaf(wq, __uint_as_float((Q).y << 16), a2); \
            a3 = fmaf(wq, __uint_as_float((Q).y), a3); \
            a4 = fmaf(wq, __uint_as_float((Q).z << 16), a4); \
            a5 = fmaf(wq, __uint_as_float((Q).z), a5); \
            a6 = fmaf(wq, __uint_as_float((Q).w << 16), a6); \
            a7 = fmaf(wq, __uint_as_float((Q).w), a7); \
        }
        ACC8(q000, c000); ACC8(q001, c001); ACC8(q010, c010); ACC8(q011, c011);
        ACC8(q100, c100); ACC8(q101, c101); ACC8(q110, c110); ACC8(q111, c111);
        #undef ACC8
    }
    size_t voxOut = voxBase + yy*W_ + xx;
    unsigned r01 = pkhi(a1, a0);
    unsigned r23 = pkhi(a3, a2);
    unsigned r45 = pkhi(a5, a4);
    unsigned r67 = pkhi(a7, a6);
    *(uint4*)&coreB[voxOut*64 + g*32 + ch4] = make_uint4(r01, r23, r45, r67);
}

// out = x + sigmoid(gate) * (core @ W2 + B2), back to NCDHW  (core in bf16)
__global__ __launch_bounds__(256) void k_final(const unsigned short* __restrict__ coreB,
        const float* __restrict__ W2, const float* __restrict__ B2,
        const float* __restrict__ x, const float* __restrict__ gate,
        float* __restrict__ out) {
    __shared__ float lc[64][65];   // [v][c]
    __shared__ float lw[64][65];   // [c][o]
    int b = blockIdx.x;
    int n = b / 1152;
    int s0 = (b % 1152) * 64;
    int tid = threadIdx.x;
    for (int idx = tid; idx < 512; idx += 256) {
        int r = idx >> 3, q8 = (idx & 7) * 8;
        uint4 q = *(const uint4*)&coreB[((size_t)(n*S_ + s0 + r))*64 + q8];
        lc[r][q8+0] = __uint_as_float(q.x << 16);
        lc[r][q8+1] = __uint_as_float(q.x & 0xffff0000u);
        lc[r][q8+2] = __uint_as_float(q.y << 16);
        lc[r][q8+3] = __uint_as_float(q.y & 0xffff0000u);
        lc[r][q8+4] = __uint_as_float(q.z << 16);
        lc[r][q8+5] = __uint_as_float(q.z & 0xffff0000u);
        lc[r][q8+6] = __uint_as_float(q.w << 16);
        lc[r][q8+7] = __uint_as_float(q.w & 0xffff0000u);
    }
    for (int idx = tid; idx < 1024; idx += 256) {
        int r = idx >> 4, q4 = (idx & 15) * 4;
        float4 vw = *(const float4*)&W2[r*64 + q4];
        lw[r][q4] = vw.x; lw[r][q4+1] = vw.y; lw[r][q4+2] = vw.z; lw[r][q4+3] = vw.w;
    }
    __syncthreads();
    float sg = 1.f / (1.f + expf(-gate[0]));
    int o0 = (tid & 15) * 4;
    int v0 = (tid >> 4) * 4;
    float acc[4][4];
    #pragma unroll
    for (int oj = 0; oj < 4; ++oj) {
        float bo = B2[o0+oj];
        #pragma unroll
        for (int vj = 0; vj < 4; ++vj) acc[vj][oj] = bo;
    }
    #pragma unroll 8
    for (int c = 0; c < 64; ++c) {
        float fv[4], wv[4];
        #pragma unroll
        for (int j = 0; j < 4; ++j) { fv[j] = lc[v0+j][c]; wv[j] = lw[c][o0+j]; }
        #pragma unroll
        for (int vj = 0; vj < 4; ++vj)
            #pragma unroll
            for (int oj = 0; oj < 4; ++oj)
                acc[vj][oj] = fmaf(fv[vj], wv[oj], acc[vj][oj]);
    }
    #pragma unroll
    for (int oj = 0; oj < 4; ++oj) {
        size_t gi = ((size_t)(n*64 + o0 + oj))*S_ + s0 + v0;
        float4 xv = *(const float4*)&x[gi];
        float4 r;
        r.x = fmaf(sg, acc[0][oj], xv.x);
        r.y = fmaf(sg, acc[1][oj], xv.y);
        r.z = fmaf(sg, acc[2][oj], xv.z);
        r.w = fmaf(sg, acc[3][oj], xv.w);
        *(float4*)&out[gi] = r;
    }
}

extern "C" void kernel_launch(void* const* d_in, const int* in_sizes, int n_in,
                              void* d_out, int out_size, void* d_ws, size_t ws_size,
                              hipStream_t stream) {
    const float* x      = (const float*)d_in[0];
    const float* w_pre  = (const float*)d_in[1];
    const float* w_in   = (const float*)d_in[2];
    const float* b_in   = (const float*)d_in[3];
    const float* w_dw   = (const float*)d_in[4];
    const float* w_off  = (const float*)d_in[5];
    const float* b_off  = (const float*)d_in[6];
    const float* w_mask = (const float*)d_in[7];
    const float* b_mask = (const float*)d_in[8];
    const float* w_out  = (const float*)d_in[9];
    const float* b_out  = (const float*)d_in[10];
    const float* w_post = (const float*)d_in[11];
    const float* gate   = (const float*)d_in[12];
    float* out = (float*)d_out;

    float* ws      = (float*)d_ws;
    unsigned short* xprojP = (unsigned short*)ws;      // 15,360,000 ushorts
    float* pre     = ws + (size_t)7680000;             // 9,437,184 floats
    unsigned short* coreB = (unsigned short*)(pre + (size_t)9437184);  // 9,437,184 ushorts
    float* psum    = (float*)(coreB + (size_t)9437184);// 98,304
    float* pss     = psum + 98304;                     // 98,304
    float* stats   = pss + 98304;                      // 256
    float* W2      = stats + 256;                      // 4,096
    float* B2      = W2 + 4096;                        // 64 (+pad)
    unsigned short* wBg = (unsigned short*)(B2 + 128); // 224*64 ushorts = 7168 floats
    float4* b4f    = (float4*)(B2 + 128 + 7168);       // 54 float4
    float* dwb     = out;                              // d_out doubles as dw scratch

    hipMemsetAsync(xprojP, 0, (size_t)15360000*sizeof(unsigned short), stream);
    hipLaunchKernelGGL(k_prep,     dim3(64),   dim3(64),  0, stream,
                       w_out, b_out, w_post, w_off, b_off, w_mask, b_mask,
                       W2, B2, wBg, b4f);
    hipLaunchKernelGGL(k_pre_proj, dim3(2304), dim3(256), 0, stream,
                       x, w_pre, w_in, b_in, pre, xprojP);
    hipLaunchKernelGGL(k_dw_stats, dim3(1536), dim3(256), 0, stream,
                       pre, w_dw, dwb, psum, pss);
    hipLaunchKernelGGL(k_stats2,   dim3(128),  dim3(64),  0, stream, psum, pss, stats);
    hipLaunchKernelGGL(k_dcn,      dim3(4608), dim3(256), 0, stream,
                       xprojP, dwb, stats, wBg, b4f, coreB);
    hipLaunchKernelGGL(k_final,    dim3(2304), dim3(256), 0, stream,
                       coreB, W2, B2, x, gate, out);
}

// Round 9
// 314.590 us; speedup vs baseline: 3.2426x; 1.0316x over previous
//
#include <hip/hip_runtime.h>
#include <math.h>

#define N_ 2
#define C_ 64
#define D_ 8
#define H_ 96
#define W_ 96
#define S_ (D_*H_*W_)   // 73728
#define HW_ (H_*W_)     // 9216
// padded xproj (f16): [n][z+2 of 12][y+2 of 100][x+2 of 100][64]
#define ZP_ 12
#define YP_ 100
#define XP_ 100
#define NSTR_ (ZP_*YP_*XP_*64)   // 7680000 elements
#define ZS_ (YP_*XP_*64)         // 640000
#define YS_ (XP_*64)             // 6400

typedef __attribute__((ext_vector_type(8))) short short8;
typedef __attribute__((ext_vector_type(4))) float f32x4;
typedef __attribute__((ext_vector_type(2))) __fp16 h2;

union U32H2 { unsigned u; h2 h; unsigned short s[2]; };
__device__ __forceinline__ h2 uAsH2(unsigned u){ U32H2 t; t.u = u; return t.h; }
__device__ __forceinline__ unsigned h2AsU(h2 h){ U32H2 t; t.h = h; return t.u; }

__device__ __forceinline__ float dot2f(unsigned u, h2 w, float acc) {
#if __has_builtin(__builtin_amdgcn_fdot2)
    return __builtin_amdgcn_fdot2(uAsH2(u), w, acc, false);
#else
    h2 v = uAsH2(u);
    return fmaf((float)v.y, (float)w.y, fmaf((float)v.x, (float)w.x, acc));
#endif
}

__device__ __forceinline__ float gelu_fast(float x) {
    float a = 0.7978845608028654f * (x + 0.044715f*x*x*x);
    float E = __expf(2.f*a);
    return x - x * __builtin_amdgcn_rcpf(E + 1.f);
}

__device__ __forceinline__ unsigned short f2bf(float f) {   // RNE bf16
    unsigned u = __float_as_uint(f);
    unsigned r = (u + 0x7fffu + ((u >> 16) & 1u)) >> 16;
    return (unsigned short)r;
}

__device__ __forceinline__ unsigned short f2h(float f) {    // f32 -> f16 bits
    U32H2 t; t.h[0] = (__fp16)f; t.h[1] = (__fp16)0.f; return t.s[0];
}

// prep: W2 = w_out @ w_post^T (f16-transposed), B2; wBg bf16 proj weights; b4f biases
__global__ __launch_bounds__(64) void k_prep(const float* __restrict__ w_out,
        const float* __restrict__ b_out, const float* __restrict__ w_post,
        const float* __restrict__ w_off, const float* __restrict__ b_off,
        const float* __restrict__ w_mask, const float* __restrict__ b_mask,
        float* __restrict__ B2, unsigned short* __restrict__ W2T,
        unsigned short* __restrict__ wBg, float4* __restrict__ b4f) {
    int b = blockIdx.x;      // 0..63  (= core-channel c2)
    int t = threadIdx.x;     // 0..63  (= output o)
    float acc = 0.f;
    for (int c = 0; c < 64; ++c)
        acc = fmaf(w_out[b*64+c], w_post[t*64+c], acc);
    W2T[t*64 + b] = f2h(acc);          // W2T[o][c2] f16
    if (b == 0) {
        float a2 = 0.f;
        for (int c = 0; c < 64; ++c)
            a2 = fmaf(w_post[t*64+c], b_out[c], a2);
        B2[t] = a2;
    }
    {
        int c = b;
        for (int m = t; m < 224; m += 64) {
            float v = 0.f;
            if (m < 216) {
                int u = m >> 2, comp = m & 3;
                if (comp == 3) v = w_mask[c*54 + u];
                else {
                    v = w_off[c*162 + u*3 + comp];
                    if (comp == 0) v *= 0.5f;
                }
            }
            wBg[m*64 + c] = f2bf(v);
        }
    }
    if (b == 1 && t < 54)
        b4f[t] = make_float4(b_off[t*3]*0.5f, b_off[t*3+1], b_off[t*3+2], b_mask[t]);
}

// fused: pre = x @ w_pre^T (fp32, for dw), xprojP = f16(pre @ w_in + b_in) padded
__global__ __launch_bounds__(256) void k_pre_proj(const float* __restrict__ x,
        const float* __restrict__ w_pre, const float* __restrict__ w_in,
        const float* __restrict__ b_in, float* __restrict__ pre,
        unsigned short* __restrict__ xprojP) {
    __shared__ float lx[64][65];    // [c][v] then reused as [v][c2]
    __shared__ float lwa[64][65];   // w_pre [o][c]
    __shared__ float lwb[64][65];   // w_in  [c][o]
    int b = blockIdx.x;
    int n = b / 1152;
    int s0 = (b % 1152) * 64;
    int tid = threadIdx.x;
    for (int idx = tid; idx < 1024; idx += 256) {
        int r = idx >> 4, q4 = (idx & 15) * 4;
        float4 vx = *(const float4*)&x[((size_t)(n*C_ + r))*S_ + s0 + q4];
        lx[r][q4] = vx.x; lx[r][q4+1] = vx.y; lx[r][q4+2] = vx.z; lx[r][q4+3] = vx.w;
        float4 va = *(const float4*)&w_pre[r*64 + q4];
        lwa[r][q4] = va.x; lwa[r][q4+1] = va.y; lwa[r][q4+2] = va.z; lwa[r][q4+3] = va.w;
        float4 vb = *(const float4*)&w_in[r*64 + q4];
        lwb[r][q4] = vb.x; lwb[r][q4+1] = vb.y; lwb[r][q4+2] = vb.z; lwb[r][q4+3] = vb.w;
    }
    __syncthreads();
    int o0 = (tid & 15) * 4;
    int v0 = (tid >> 4) * 4;
    float acc[4][4] = {};
    #pragma unroll 8
    for (int c = 0; c < 64; ++c) {
        float xv[4], wv[4];
        #pragma unroll
        for (int j = 0; j < 4; ++j) { xv[j] = lx[c][v0+j]; wv[j] = lwa[o0+j][c]; }
        #pragma unroll
        for (int vj = 0; vj < 4; ++vj)
            #pragma unroll
            for (int oj = 0; oj < 4; ++oj)
                acc[vj][oj] = fmaf(xv[vj], wv[oj], acc[vj][oj]);
    }
    #pragma unroll
    for (int vj = 0; vj < 4; ++vj) {
        float4 r = make_float4(acc[vj][0], acc[vj][1], acc[vj][2], acc[vj][3]);
        *(float4*)&pre[((size_t)(n*S_ + s0 + v0 + vj))*64 + o0] = r;
    }
    __syncthreads();
    #pragma unroll
    for (int vj = 0; vj < 4; ++vj)
        #pragma unroll
        for (int oj = 0; oj < 4; ++oj)
            lx[v0+vj][o0+oj] = acc[vj][oj];   // lx = pre tile [v][c2]
    __syncthreads();
    float acc2[4][4];
    #pragma unroll
    for (int oj = 0; oj < 4; ++oj) {
        float bo = b_in[o0+oj];
        #pragma unroll
        for (int vj = 0; vj < 4; ++vj) acc2[vj][oj] = bo;
    }
    #pragma unroll 8
    for (int c = 0; c < 64; ++c) {
        float fv[4], wv[4];
        #pragma unroll
        for (int j = 0; j < 4; ++j) { fv[j] = lx[v0+j][c]; wv[j] = lwb[c][o0+j]; }
        #pragma unroll
        for (int vj = 0; vj < 4; ++vj)
            #pragma unroll
            for (int oj = 0; oj < 4; ++oj)
                acc2[vj][oj] = fmaf(fv[vj], wv[oj], acc2[vj][oj]);
    }
    #pragma unroll
    for (int vj = 0; vj < 4; ++vj) {
        int vox = s0 + v0 + vj;      // within image n
        int z = vox / HW_;
        int rem = vox - z*HW_;
        int y = rem / W_;
        int xq = rem - y*W_;
        size_t pw = (size_t)n*NSTR_ + (size_t)(z+2)*ZS_ + (y+2)*YS_ + (xq+2)*64 + o0;
        unsigned lo = h2AsU(__builtin_amdgcn_cvt_pkrtz(acc2[vj][0], acc2[vj][1]));
        unsigned hi = h2AsU(__builtin_amdgcn_cvt_pkrtz(acc2[vj][2], acc2[vj][3]));
        *(uint2*)&xprojP[pw] = make_uint2(lo, hi);
    }
}

// depthwise 3x3x3 + instance-norm partials; 4 channels per thread, float4 loads
__global__ __launch_bounds__(256) void k_dw_stats(const float* __restrict__ pre,
        const float* __restrict__ w_dw, float* __restrict__ dw,
        float* __restrict__ psum, float* __restrict__ pss) {
    __shared__ float4 lwd[27][16];     // [tap][c4]
    __shared__ float4 lsum[16][16];    // [xg][c4]
    __shared__ float4 lssum[16][16];
    int b = blockIdx.x;               // n*D*H + z*H + y  (1536)
    int y = b % H_;
    int z = (b / H_) % D_;
    int n = b / (D_*H_);
    int tid = threadIdx.x;
    if (tid < 27*16) {
        int k = tid >> 4, c4 = tid & 15;
        lwd[k][c4] = make_float4(w_dw[(c4*4+0)*27 + k], w_dw[(c4*4+1)*27 + k],
                                 w_dw[(c4*4+2)*27 + k], w_dw[(c4*4+3)*27 + k]);
    }
    __syncthreads();
    int c4 = tid & 15, xg = tid >> 4;
    const float* preN = pre + (size_t)n*S_*64;
    float4 s4 = make_float4(0,0,0,0), ss4 = make_float4(0,0,0,0);
    for (int xx = 0; xx < 6; ++xx) {
        int xi = xg + xx*16;
        float4 acc = make_float4(0,0,0,0);
        #pragma unroll
        for (int dz = 0; dz < 3; ++dz) {
            int zz = z + dz - 1;
            if (zz < 0 || zz >= D_) continue;
            #pragma unroll
            for (int dy = 0; dy < 3; ++dy) {
                int yy = y + dy - 1;
                if (yy < 0 || yy >= H_) continue;
                int rowb = (zz*HW_ + yy*W_)*64 + c4*4;
                #pragma unroll
                for (int dx = 0; dx < 3; ++dx) {
                    int xn = xi + dx - 1;
                    if ((unsigned)xn < (unsigned)W_) {
                        float4 v = *(const float4*)&preN[rowb + (xn<<6)];
                        float4 w = lwd[dz*9+dy*3+dx][c4];
                        acc.x = fmaf(v.x, w.x, acc.x);
                        acc.y = fmaf(v.y, w.y, acc.y);
                        acc.z = fmaf(v.z, w.z, acc.z);
                        acc.w = fmaf(v.w, w.w, acc.w);
                    }
                }
            }
        }
        *(float4*)&dw[((size_t)n*S_ + z*HW_ + y*W_ + xi)*64 + c4*4] = acc;
        s4.x += acc.x; s4.y += acc.y; s4.z += acc.z; s4.w += acc.w;
        ss4.x = fmaf(acc.x, acc.x, ss4.x); ss4.y = fmaf(acc.y, acc.y, ss4.y);
        ss4.z = fmaf(acc.z, acc.z, ss4.z); ss4.w = fmaf(acc.w, acc.w, ss4.w);
    }
    lsum[xg][c4] = s4; lssum[xg][c4] = ss4;
    __syncthreads();
    if (tid < 64) {
        float s = 0.f, ss = 0.f;
        #pragma unroll
        for (int k = 0; k < 16; ++k) {
            s  += ((const float*)&lsum [k][tid>>2])[tid&3];
            ss += ((const float*)&lssum[k][tid>>2])[tid&3];
        }
        psum[tid*1536 + b] = s;
        pss [tid*1536 + b] = ss;
    }
}

// reduce partials -> mean / rsqrt(var)
__global__ void k_stats2(const float* __restrict__ psum, const float* __restrict__ pss,
                         float* __restrict__ stats) {
    int u = blockIdx.x;               // 0..127
    int n = u >> 6, c = u & 63;
    int l = threadIdx.x;              // 0..63
    float s = 0.f, ss = 0.f;
    #pragma unroll
    for (int k = 0; k < 12; ++k) {
        int row = n*768 + k*64 + l;
        s  += psum[c*1536 + row];
        ss += pss [c*1536 + row];
    }
    #pragma unroll
    for (int o2 = 32; o2 >= 1; o2 >>= 1) {
        s  += __shfl_xor(s, o2);
        ss += __shfl_xor(ss, o2);
    }
    if (l == 0) {
        float inv = 1.f / (float)S_;
        float mean = s * inv;
        float var = ss * inv - mean*mean;
        stats[n*128 + c] = mean;
        stats[n*128 + 64 + c] = rsqrtf(var + 1e-5f);
    }
}

// fused DCN + output GEMM: block = 1z x 4y x 8x = 32 voxels (64 pairs)
__global__ __launch_bounds__(256) void k_dcn(const unsigned short* __restrict__ xprojP,
        const float* __restrict__ dw, const float* __restrict__ stats,
        const unsigned short* __restrict__ wBg, const float4* __restrict__ b4f,
        const unsigned short* __restrict__ W2T, const float* __restrict__ B2,
        const float* __restrict__ xin, const float* __restrict__ gate,
        float* __restrict__ out) {
    __shared__ uint4 descW[27][64];     // phase1: float4 offs (dx,dy,dz,logit/prob); phase2: f16 wpairs
    __shared__ union {
        unsigned short featB[32][64];   // 1a/1b: bf16 feat (swizzled 16B blocks)
        int cwl[27][64];                // 2a/2b: base element offsets
        unsigned short coreT[32][64];   // phase4: f16 core (swizzled 16B blocks)
    } uS;
    int tid = threadIdx.x;
    // bijective XCD swizzle: 4608 blocks = 8 * 576
    int orig = blockIdx.x;
    int bid = (orig & 7) * 576 + (orig >> 3);
    int x8 = bid % 12;
    int t1 = bid / 12;
    int y4 = t1 % 24;
    int t2 = t1 / 24;                 // 0..15
    int z  = t2 & 7;
    int n  = t2 >> 3;
    int yb = y4*4, xb = x8*8;
    size_t voxBase = (size_t)n*S_ + (size_t)z*HW_ + yb*W_ + xb;
    float4* offsF = (float4*)descW;

    // 1a: feat = gelu(instnorm(dw)) -> bf16 featB[vox][k] (swizzled 16B blocks)
    {
        int c4 = (tid & 15) * 4;
        int vp = tid >> 4;
        #pragma unroll
        for (int j = 0; j < 2; ++j) {
            int vloc = vp*2 + j;
            size_t vox = voxBase + (vloc>>3)*W_ + (vloc & 7);
            float4 v = *(const float4*)&dw[vox*64 + c4];
            float vals[4] = {v.x, v.y, v.z, v.w};
            ushort4 pk;
            unsigned short* pp = (unsigned short*)&pk;
            #pragma unroll
            for (int jj = 0; jj < 4; ++jj) {
                int c = c4 + jj;
                float t = (vals[jj] - stats[n*128+c]) * stats[n*128+64+c];
                pp[jj] = f2bf(gelu_fast(t));
            }
            int off = ((((c4 >> 3) ^ (vloc & 7)) << 3) | (c4 & 7));
            *(ushort4*)&uS.featB[vloc][off] = pk;
        }
    }
    __syncthreads();

    // 1b: MFMA projection. D[224][32] = wBg[224x64] @ featB[64x32]
    {
        int w = tid >> 6;
        int l = tid & 63;
        int lr = l & 15;
        int lq = l >> 4;
        for (int i = 0; i < 7; ++i) {
            int t7 = w*7 + i;
            int mt = t7 >> 1, nt = t7 & 1;
            int vox = nt*16 + lr;
            f32x4 acc = {0.f, 0.f, 0.f, 0.f};
            #pragma unroll
            for (int h = 0; h < 2; ++h) {
                int k0 = h*32 + lq*8;
                short8 af = *(const short8*)&wBg[(mt*16 + lr)*64 + k0];
                int blk = (((k0 >> 3) ^ (vox & 7)) << 3);
                short8 bf = *(const short8*)&uS.featB[vox][blk];
                acc = __builtin_amdgcn_mfma_f32_16x16x32_bf16(af, bf, acc, 0, 0, 0);
            }
            int u = mt*4 + lq;
            if (u < 54) {
                float4 bb = b4f[u];
                int g = (u >= 27) ? 1 : 0;
                int p = u - g*27;
                offsF[p*64 + vox*2 + g] = make_float4(acc[0] + bb.x, acc[1] + bb.y,
                                                      acc[2] + bb.z, acc[3] + bb.w);
            }
        }
    }
    __syncthreads();

    // softmax over taps per pair (64 pairs)
    if (tid < 64) {
        int pair = tid;
        float mx = -1e30f;
        #pragma unroll
        for (int p = 0; p < 27; ++p) mx = fmaxf(mx, offsF[p*64 + pair].w);
        float e[27]; float ssum = 0.f;
        #pragma unroll
        for (int p = 0; p < 27; ++p) {
            e[p] = __expf(offsF[p*64 + pair].w - mx);
            ssum += e[p];
        }
        float inv = __builtin_amdgcn_rcpf(ssum);
        #pragma unroll
        for (int p = 0; p < 27; ++p) {
            float4 t = offsF[p*64 + pair];
            t.w = e[p]*inv;
            offsF[p*64 + pair] = t;
        }
    }
    __syncthreads();

    // 2a: tap descriptors — 4 packed f16 weight pairs + base offset, once per (pair,tap)
    {
        int zm1 = z - 1;
        #pragma unroll
        for (int k = 0; k < 7; ++k) {
            int idx = tid + k*256;
            if (idx < 1728) {
                int pair = idx & 63;
                int p = idx >> 6;
                float4 tp = offsF[p*64 + pair];
                int vloc = pair >> 1, g = pair & 1;
                int yy = vloc >> 3, xx = vloc & 7;
                float zf = (float)(zm1 + p/9) + tp.z;
                float yf = (float)(yb + yy - 1 + (p/3)%3) + tp.y;
                float xf = (float)(xb + xx - 1 + p%3) + tp.x;
                zf = fminf(fmaxf(zf, -1.5f), (float)D_ + 0.5f);
                yf = fminf(fmaxf(yf, -1.5f), (float)H_ + 0.5f);
                xf = fminf(fmaxf(xf, -1.5f), (float)W_ + 0.5f);
                float z0f = floorf(zf), y0f = floorf(yf), x0f = floorf(xf);
                float fz = zf - z0f, fy = yf - y0f, fx = xf - x0f;
                int zi = (int)z0f, yi = (int)y0f, xi = (int)x0f;
                float wz1 = fz * tp.w, wz0 = tp.w - wz1;   // prob folded in
                float wy1 = fy, wy0 = 1.f - fy;
                float wx1 = fx, wx0 = 1.f - fx;
                float w00 = wz0*wy0, w01 = wz0*wy1, w10 = wz1*wy0, w11 = wz1*wy1;
                unsigned u0 = h2AsU(__builtin_amdgcn_cvt_pkrtz(w00*wx0, w00*wx1));
                unsigned u1 = h2AsU(__builtin_amdgcn_cvt_pkrtz(w01*wx0, w01*wx1));
                unsigned u2 = h2AsU(__builtin_amdgcn_cvt_pkrtz(w10*wx0, w10*wx1));
                unsigned u3 = h2AsU(__builtin_amdgcn_cvt_pkrtz(w11*wx0, w11*wx1));
                int cw = zi*ZS_ + yi*YS_ + (xi<<6) + (2*ZS_ + 2*YS_ + 128) + g*32;
                descW[p][pair] = make_uint4(u0, u1, u2, u3);
                uS.cwl[p][pair] = cw;
            }
        }
    }
    __syncthreads();

    // 2b: gather — 4 lanes x 8 f16 channels per (voxel,g); dot2 over x-corner pairs
    int pair = tid >> 2;              // 0..63
    int vloc = pair >> 1, g = pair & 1;
    int ch4 = (tid & 3) * 8;          // channel offset within group
    const unsigned short* __restrict__ base = xprojP + (size_t)n*NSTR_ + ch4;
    float a0=0.f,a1=0.f,a2=0.f,a3=0.f,a4=0.f,a5=0.f,a6=0.f,a7=0.f;
    #pragma unroll
    for (int p = 0; p < 27; ++p) {
        uint4 wp = descW[p][pair];
        int cw = uS.cwl[p][pair];
        const unsigned short* p00 = base + cw;
        const unsigned short* p01 = p00 + YS_;
        const unsigned short* p10 = p00 + ZS_;
        const unsigned short* p11 = p10 + YS_;
        uint4 qa0 = *(const uint4*)p00;
        uint4 qa1 = *(const uint4*)(p00 + 64);
        uint4 qb0 = *(const uint4*)p01;
        uint4 qb1 = *(const uint4*)(p01 + 64);
        uint4 qc0 = *(const uint4*)p10;
        uint4 qc1 = *(const uint4*)(p10 + 64);
        uint4 qd0 = *(const uint4*)p11;
        uint4 qd1 = *(const uint4*)(p11 + 64);
        h2 w0 = uAsH2(wp.x), w1 = uAsH2(wp.y), w2 = uAsH2(wp.z), w3 = uAsH2(wp.w);
        // perm sel: lo-ch pair = {A.b0,A.b1,B.b0,B.b1} -> 0x01000504 ; hi-ch -> 0x03020706
        #define CP(QA, QB, WH) { \
            a0 = dot2f(__builtin_amdgcn_perm(QA.x, QB.x, 0x01000504u), WH, a0); \
            a1 = dot2f(__builtin_amdgcn_perm(QA.x, QB.x, 0x03020706u), WH, a1); \
            a2 = dot2f(__builtin_amdgcn_perm(QA.y, QB.y, 0x01000504u), WH, a2); \
            a3 = dot2f(__builtin_amdgcn_perm(QA.y, QB.y, 0x03020706u), WH, a3); \
            a4 = dot2f(__builtin_amdgcn_perm(QA.z, QB.z, 0x01000504u), WH, a4); \
            a5 = dot2f(__builtin_amdgcn_perm(QA.z, QB.z, 0x03020706u), WH, a5); \
            a6 = dot2f(__builtin_amdgcn_perm(QA.w, QB.w, 0x01000504u), WH, a6); \
            a7 = dot2f(__builtin_amdgcn_perm(QA.w, QB.w, 0x03020706u), WH, a7); \
        }
        CP(qa0, qa1, w0); CP(qb0, qb1, w1); CP(qc0, qc1, w2); CP(qd0, qd1, w3);
        #undef CP
    }
    __syncthreads();   // done reading cwl; reuse union as coreT

    // 3: pack core to f16 into coreT[vox][c] (swizzled 16B blocks)
    {
        unsigned c01 = h2AsU(__builtin_amdgcn_cvt_pkrtz(a0, a1));
        unsigned c23 = h2AsU(__builtin_amdgcn_cvt_pkrtz(a2, a3));
        unsigned c45 = h2AsU(__builtin_amdgcn_cvt_pkrtz(a4, a5));
        unsigned c67 = h2AsU(__builtin_amdgcn_cvt_pkrtz(a6, a7));
        int col = g*32 + ch4;
        int blk = (((col >> 3) ^ (vloc & 7)) << 3);
        *(uint4*)&uS.coreT[vloc][blk] = make_uint4(c01, c23, c45, c67);
    }
    __syncthreads();

    // 4: output GEMM via MFMA: out[32 vox][64 o] = coreT @ W2T^T ; +bias, +residual
    {
        int w = tid >> 6, l = tid & 63, lr = l & 15, lq = l >> 4;
        float sg = 1.f / (1.f + __expf(-gate[0]));
        #pragma unroll
        for (int t = 0; t < 2; ++t) {
            int tile = w*2 + t;
            int mt = tile >> 2, nt = tile & 3;
            int o = nt*16 + lr;
            f32x4 acc = {0.f, 0.f, 0.f, 0.f};
            #pragma unroll
            for (int h = 0; h < 2; ++h) {
                int k0 = h*32 + lq*8;
                int arow = mt*16 + lr;
                int blk = (((k0 >> 3) ^ (arow & 7)) << 3);
                short8 af = *(const short8*)&uS.coreT[arow][blk];
                short8 bf = *(const short8*)&W2T[o*64 + k0];
                acc = __builtin_amdgcn_mfma_f32_16x16x32_f16(af, bf, acc, 0, 0, 0);
            }
            float b2 = B2[o];
            int vox0 = mt*16 + lq*4;
            int yy = vox0 >> 3, xx0 = vox0 & 7;
            size_t gi = ((size_t)(n*64 + o))*S_ + (size_t)z*HW_ + (size_t)(yb+yy)*W_ + (xb+xx0);
            float4 xv = *(const float4*)&xin[gi];
            float4 r;
            r.x = fmaf(sg, acc[0] + b2, xv.x);
            r.y = fmaf(sg, acc[1] + b2, xv.y);
            r.z = fmaf(sg, acc[2] + b2, xv.z);
            r.w = fmaf(sg, acc[3] + b2, xv.w);
            *(float4*)&out[gi] = r;
        }
    }
}

extern "C" void kernel_launch(void* const* d_in, const int* in_sizes, int n_in,
                              void* d_out, int out_size, void* d_ws, size_t ws_size,
                              hipStream_t stream) {
    const float* x      = (const float*)d_in[0];
    const float* w_pre  = (const float*)d_in[1];
    const float* w_in   = (const float*)d_in[2];
    const float* b_in   = (const float*)d_in[3];
    const float* w_dw   = (const float*)d_in[4];
    const float* w_off  = (const float*)d_in[5];
    const float* b_off  = (const float*)d_in[6];
    const float* w_mask = (const float*)d_in[7];
    const float* b_mask = (const float*)d_in[8];
    const float* w_out  = (const float*)d_in[9];
    const float* b_out  = (const float*)d_in[10];
    const float* w_post = (const float*)d_in[11];
    const float* gate   = (const float*)d_in[12];
    float* out = (float*)d_out;

    float* ws      = (float*)d_ws;
    unsigned short* xprojP = (unsigned short*)ws;      // 15,360,000 ushorts (30.7MB)
    float* pre     = ws + (size_t)7680000;             // 9,437,184 floats
    float* dwb     = pre + (size_t)9437184;            // 9,437,184 floats (dw scratch)
    float* psum    = dwb + (size_t)9437184;            // 98,304
    float* pss     = psum + 98304;                     // 98,304
    float* stats   = pss + 98304;                      // 256
    float* B2      = stats + 256;                      // 64 (+pad)
    unsigned short* W2T = (unsigned short*)(B2 + 128); // 64*64 ushorts = 2048 floats
    unsigned short* wBg = W2T + 4096;                  // 224*64 ushorts
    float4* b4f    = (float4*)(wBg + 14336 + 64);      // 54 float4

    (void)hipMemsetAsync(xprojP, 0, (size_t)15360000*sizeof(unsigned short), stream);
    hipLaunchKernelGGL(k_prep,     dim3(64),   dim3(64),  0, stream,
                       w_out, b_out, w_post, w_off, b_off, w_mask, b_mask,
                       B2, W2T, wBg, b4f);
    hipLaunchKernelGGL(k_pre_proj, dim3(2304), dim3(256), 0, stream,
                       x, w_pre, w_in, b_in, pre, xprojP);
    hipLaunchKernelGGL(k_dw_stats, dim3(1536), dim3(256), 0, stream,
                       pre, w_dw, dwb, psum, pss);
    hipLaunchKernelGGL(k_stats2,   dim3(128),  dim3(64),  0, stream, psum, pss, stats);
    hipLaunchKernelGGL(k_dcn,      dim3(4608), dim3(256), 0, stream,
                       xprojP, dwb, stats, wBg, b4f, W2T, B2, x, gate, out);
}